// Round 4
// baseline (162.098 us; speedup 1.0000x reference)
//
#include <hip/hip_runtime.h>

#define DIM 4096
using F2 = float2;

// R17 = R16 dataflow (layouts/packings/schedule harness-verified correct)
// with register pressure cut to fit 8 waves/SIMD:
//  - fused gates split into two g1q passes over the compile-time disjoint
//    MSEL subsets (matrix-A pairs, then matrix-B pairs) -> only 8 coeff
//    VGPRs live instead of 16; arithmetic per pair identical.
//  - lane-bit / tile-pointer computation scoped inside each transpose.
//  - __launch_bounds__(256, 8): VGPR cap 64 (HW occupancy quantum: <=64 ->
//    8 waves/SIMD). R16's (256,6) made the allocator dump amp[] to scratch
//    (VGPR=40, WRITE_SIZE 106 MB, 10x HBM traffic) -> 86 us. Target here:
//    VGPR <= 64, WRITE_SIZE ~128 KB, occupancy ~60-90%.
//
// Address bits: qubit q <-> a[11-q]. Layouts (reg bit value in parens):
//  A : regs a11(8) a10(4) a9(2) a8(1); lanes a7..a2=l5..l0; wave a1a0
//      masks: q0:8 q1:4 q2:2 q3:1
//  B : regs a8(1) a7(4) a6(8) a5(2); lanes a11,a10,a9,a4,a3,a2=l5..l0; wave a1a0
//      masks: q3:1 q4:4 q5:8 q6:2
//  C : regs a5(2) a4(4) a3(8) a2(1); lanes a11..a6=l5..l0; wave a1a0
//      masks: q6:2 q7:4 q8:8 q9:1
//  D : regs a2(1) a1(2) a0(4) a11(8); lanes a10,a9,a8,a5,a4,a3=l5..l0; wave a7a6
//      masks: q9:1 q10:2 q11:4 q0:8
//  C': regs as C; lanes a11,a10,a9,a8,a1,a0=l5..l0; wave a7a6
//  B': = B.   A': = A.
// Transitions: T1 A->B del a8 SB=1 internal; T2 B->C del a5 SB=2 internal;
//  T3 C->D del a2 SB=1 CROSS; T4 D->C' del a2 SB=1 internal;
//  T5 C'->B' del a5 SB=2 CROSS; T6 B'->A' del a8 SB=1 internal.
// Internal transposes: wave bits identical both sides -> same-wave lgkmcnt
// fence only. Cross transposes: real __syncthreads. 8 block barriers total.

// ---- packed fp32 complex primitives (VOP3P) — proven R8-R16 ----
__device__ __forceinline__ F2 pk_mul_bl(F2 a, F2 u) {   // (a.x*u.x, a.y*u.x)
    F2 d;
    asm("v_pk_mul_f32 %0, %1, %2 op_sel:[0,0] op_sel_hi:[1,0]"
        : "=v"(d) : "v"(a), "v"(u));
    return d;
}
__device__ __forceinline__ void pk_cross(F2& d, F2 a, F2 u) {  // d += (-a.y*u.y, a.x*u.y)
    asm("v_pk_fma_f32 %0, %1, %2, %0 op_sel:[1,1,0] op_sel_hi:[0,1,1] neg_lo:[1,0,0]"
        : "+v"(d) : "v"(a), "v"(u));
}
__device__ __forceinline__ void pk_fma_bl(F2& d, F2 a, F2 u) { // d += (a.x*u.x, a.y*u.x)
    asm("v_pk_fma_f32 %0, %1, %2, %0 op_sel:[0,0,0] op_sel_hi:[1,0,1]"
        : "+v"(d) : "v"(a), "v"(u));
}
__device__ __forceinline__ void pk_swapneg(F2& d, F2 a, F2 cs) { // d += (a.y*cs.y, -a.x*cs.y)
    asm("v_pk_fma_f32 %0, %1, %2, %0 op_sel:[1,1,0] op_sel_hi:[0,1,1] neg_hi:[1,0,0]"
        : "+v"(d) : "v"(a), "v"(cs));
}
__device__ __forceinline__ void pk_fma(F2& d, F2 a, F2 b) {    // d += a*b
    asm("v_pk_fma_f32 %0, %1, %2, %0" : "+v"(d) : "v"(a), "v"(b));
}
__device__ __forceinline__ void pk_imacc(F2& d, F2 a0, F2 a1) { // d += (a0.x*a1.y, -a0.y*a1.x)
    asm("v_pk_fma_f32 %0, %1, %2, %0 op_sel:[0,1,0] op_sel_hi:[1,0,1] neg_hi:[1,0,0]"
        : "+v"(d) : "v"(a0), "v"(a1));
}
__device__ __forceinline__ F2 pk_cmul(F2 u, F2 a) {
    F2 d = pk_mul_bl(a, u);
    pk_cross(d, a, u);
    return d;
}
__device__ __forceinline__ void pk_cfma(F2& d, F2 u, F2 a) {
    pk_fma_bl(d, a, u);
    pk_cross(d, a, u);
}

__device__ __forceinline__ void build_u(float tx, float ty, float tz, float* u) {
    float sx = sinf(0.5f*tx), cx = cosf(0.5f*tx);
    float sy = sinf(0.5f*ty), cy = cosf(0.5f*ty);
    float sz = sinf(0.5f*tz), cz = cosf(0.5f*tz);
    float A00r = cy*cx, A00i =  sy*sx;     // A = Ry*Rx
    float A01r = -sy*cx, A01i = -cy*sx;
    float A10r =  sy*cx, A10i = -cy*sx;
    float A11r =  cy*cx, A11i = -sy*sx;
    // U = Rz*A: row0 *= (cz - i sz), row1 *= (cz + i sz)   [verified r1/3/5..16]
    u[0] = cz*A00r + sz*A00i;  u[1] = cz*A00i - sz*A00r;
    u[2] = cz*A01r + sz*A01i;  u[3] = cz*A01i - sz*A01r;
    u[4] = cz*A10r - sz*A10i;  u[5] = cz*A10i + sz*A10r;
    u[6] = cz*A11r - sz*A11i;  u[7] = cz*A11i + sz*A11r;
}

// coef layout (floats): [0..95] U0 plain (q*8); [96..191] RX(ang[36+q-1])*U0[q] (q=1..11);
// [192..287] U1 plain; [288..295] U1[0]*RX(ang[47]); [296..319] L1 CRX (cos,sin)[c=0..11]
__global__ void prep_kernel(const float* __restrict__ ang, float* __restrict__ coef) {
    int t = threadIdx.x;
    if (t < 12) {
        float u[8]; build_u(ang[t], ang[12+t], ang[24+t], u);
#pragma unroll
        for (int j = 0; j < 8; ++j) coef[t*8 + j] = u[j];
    } else if (t < 24) {
        int q = t - 12;
        float u[8]; build_u(ang[48+q], ang[60+q], ang[72+q], u);
#pragma unroll
        for (int j = 0; j < 8; ++j) coef[192 + q*8 + j] = u[j];
    } else if (t < 36) {
        int c = t - 24;
        float th = 0.5f * ang[95 - c];     // L1 ring gate (c,c+1) = tape slot 84+(11-c)
        coef[296 + c*2]     = cosf(th);
        coef[296 + c*2 + 1] = sinf(th);
    } else if (t < 47) {
        int q = t - 35;                    // 1..11: M = RX(ang[36+q-1]) * U0[q]
        float u[8]; build_u(ang[q], ang[12+q], ang[24+q], u);
        float c = cosf(0.5f*ang[36+q-1]), s = sinf(0.5f*ang[36+q-1]);
        float m[8];
        m[0] = c*u[0] + s*u[5];  m[1] = c*u[1] - s*u[4];   // M00 = c u00 - i s u10
        m[2] = c*u[2] + s*u[7];  m[3] = c*u[3] - s*u[6];   // M01 = c u01 - i s u11
        m[4] = s*u[1] + c*u[4];  m[5] = -s*u[0] + c*u[5];  // M10 = -i s u00 + c u10
        m[6] = s*u[3] + c*u[6];  m[7] = -s*u[2] + c*u[7];  // M11 = -i s u01 + c u11
#pragma unroll
        for (int j = 0; j < 8; ++j) coef[96 + q*8 + j] = m[j];
    } else if (t == 47) {                  // M = U1[0] * RX(ang[47])  [CR0(11,0) then U1(0)]
        float u[8]; build_u(ang[48], ang[60], ang[72], u);
        float c = cosf(0.5f*ang[47]), s = sinf(0.5f*ang[47]);
        float m[8];
        m[0] = c*u[0] + s*u[3];  m[1] = c*u[1] - s*u[2];   // M00 = c u00 - i s u01
        m[2] = s*u[1] + c*u[2];  m[3] = -s*u[0] + c*u[3];  // M01 = -i s u00 + c u01
        m[4] = c*u[4] + s*u[7];  m[5] = c*u[5] - s*u[6];   // M10 = c u10 - i s u11
        m[6] = s*u[5] + c*u[6];  m[7] = -s*u[4] + c*u[7];  // M11 = -i s u10 + c u11
#pragma unroll
        for (int j = 0; j < 8; ++j) coef[288 + j] = m[j];
    }
}

// ---- register-part (compile-time per unrolled r) of each packing ----
__device__ __forceinline__ int rpA1(int r) {   // T1/T6, A side (a8 deleted = r&1)
    int a11=(r>>3)&1, a10=(r>>2)&1, a9=(r>>1)&1;
    return (a11<<8)|(a10<<7)|(a9<<6)|(a11<<3)|(a10<<2)|(a9<<1)|(a9<<0);
}
__device__ __forceinline__ int rpB1(int r) {   // T1/T6, B side
    int a5=(r>>1)&1, a7=(r>>2)&1, a6=(r>>3)&1;
    return (a7<<5)|(a6<<4)|(a7<<3)|(a6<<2)|(a5<<0);
}
__device__ __forceinline__ int rpB2(int r) {   // T2, B side (a5 deleted = r&2)
    int a8=r&1, a7=(r>>2)&1, a6=(r>>3)&1;
    return (a8<<5)|(a7<<4)|(a6<<3)|(a7<<2)|(a8<<1)|(a6<<0);
}
__device__ __forceinline__ int rpC2(int r) {   // T2, C side
    int a2=r&1, a4=(r>>2)&1, a3=(r>>3)&1;
    return (a3<<3)|(a2<<2)|(a4<<1);
}
__device__ __forceinline__ int rpC3(int r) {   // T3/T4, C/C' side (a2 deleted = r&1)
    int a5=(r>>1)&1, a4=(r>>2)&1, a3=(r>>3)&1;
    return (a5<<4)|(a3<<3)|(a4<<2)|(a5<<0);
}
__device__ __forceinline__ int rpD3(int r) {   // T3/T4, D side
    int a1=(r>>1)&1, a0=(r>>2)&1, a11=(r>>3)&1;
    return (a11<<8)|(a11<<3)|(a1<<1)|((a0^a11)<<0);
}
__device__ __forceinline__ int rpC5(int r) {   // T5, C' side (a5 deleted = r&2)
    int a2=r&1, a4=(r>>2)&1, a3=(r>>3)&1;
    return (a4<<4)|(a3<<3)|(a2<<2)|(a4<<0);
}
__device__ __forceinline__ int rpB5(int r) {   // T5, B' side
    int a8=r&1, a7=(r>>2)&1, a6=(r>>3)&1;
    return (a7<<10)|(a6<<9)|(a8<<5)|(a8<<3);
}

// ---- tile pointers (lane/wave part of each packing); computed in scope so
// the lane-bit temporaries don't stay live across the kernel ----
#define LBITS \
    const int l0=l&1, l1=(l>>1)&1, l2=(l>>2)&1, l3=(l>>3)&1, l4=(l>>4)&1, \
              l5=(l>>5)&1, w0=w&1, w1=(w>>1)&1; \
    (void)l0;(void)l1;(void)l2;(void)l3;(void)l4;(void)l5;(void)w0;(void)w1;

__device__ __forceinline__ int tpA1f(int l, int w) { LBITS
    return (w1<<10)|(w0<<9)|(l5<<5)|(l4<<4)|((l1^l5)<<3)|((l0^l4)<<2)|(l2<<1)|(l3<<0); }
__device__ __forceinline__ int tpB1f(int l, int w) { LBITS
    return (w1<<10)|(w0<<9)|(l5<<8)|(l4<<7)|(l3<<6)|((l1^l5)<<3)|((l0^l4)<<2)|((l2^l3)<<1)|(l3<<0); }
__device__ __forceinline__ int tpC2f(int l, int w) { LBITS
    return (w1<<10)|(w0<<9)|(l5<<8)|(l4<<7)|(l3<<6)|(l2<<5)|(l1<<4)|((l5^l0)<<3)|((l4^l1)<<2)|((l3^l2)<<1)|((l0^l3)<<0); }
__device__ __forceinline__ int tpC3f(int l, int w) { LBITS
    return (l1<<10)|(l0<<9)|(l5<<8)|(l4<<7)|(l3<<6)|(l2<<5)|((l5^l4)<<3)|(l3<<2)|((w1^l2)<<1)|((w0^l5)<<0); }
__device__ __forceinline__ int tpD3f(int l, int w) { LBITS
    return (w1<<10)|(w0<<9)|(l5<<7)|(l4<<6)|(l3<<5)|(l2<<4)|((l0^l5)<<3)|((l1^l4)<<2)|(l3<<1)|(l2<<0); }
__device__ __forceinline__ int tpC4f(int l, int w) { LBITS
    return (w1<<10)|(w0<<9)|(l5<<8)|(l4<<7)|(l3<<6)|(l2<<5)|((l5^l4)<<3)|(l3<<2)|((l1^l2)<<1)|((l0^l5)<<0); }
__device__ __forceinline__ int tpC5f(int l, int w) { LBITS
    return (w1<<10)|(w0<<9)|(l5<<8)|(l4<<7)|(l3<<6)|(l2<<5)|((l5^l2)<<3)|(l4<<2)|((l1^l3)<<1)|(l0<<0); }
__device__ __forceinline__ int tpB5f(int l, int w) { LBITS
    return (l5<<8)|(l4<<7)|(l3<<6)|(l2<<4)|((l1^l5)<<3)|((l0^l4)<<2)|((w1^l3)<<1)|((w0^l2)<<0); }

// One-matrix gate pass over the compile-time subset
//   {r0 : (r0&M)==0, (S1==0 || (r0&S1)==H1), (S2==0 || (r0&S2)==H2)}.
// Fused gates are expressed as two passes (matrix-A subset, matrix-B subset)
// so only 8 coefficient VGPRs are live at a time (R16 held 16 -> spill).
template<int M, int S1, int H1, int S2, int H2>
__device__ __forceinline__ void g1q(F2* amp, const float* __restrict__ u) {
    F2 u00 = {u[0], u[1]}, u01 = {u[2], u[3]};
    F2 u10 = {u[4], u[5]}, u11 = {u[6], u[7]};
#pragma unroll
    for (int r0 = 0; r0 < 16; ++r0) {
        if (r0 & M) continue;
        if (S1 != 0 && (r0 & S1) != H1) continue;
        if (S2 != 0 && (r0 & S2) != H2) continue;
        const int r1 = r0 + M;
        F2 a0 = amp[r0], a1 = amp[r1];
        F2 n0 = pk_cmul(u00, a0); pk_cfma(n0, u01, a1);
        F2 n1 = pk_cmul(u10, a0); pk_cfma(n1, u11, a1);
        amp[r0] = n0; amp[r1] = n1;
    }
}

template<int MC, int MT>
__device__ __forceinline__ void crx(F2* amp, F2 cs) {
#pragma unroll
    for (int r0 = 0; r0 < 16; ++r0) {
        if (!(r0 & MC) || (r0 & MT)) continue;
        const int r1 = r0 + MT;
        F2 a0 = amp[r0], a1 = amp[r1];
        F2 n0 = pk_mul_bl(a0, cs); pk_swapneg(n0, a1, cs);
        F2 n1 = pk_mul_bl(a1, cs); pk_swapneg(n1, a0, cs);
        amp[r0] = n0; amp[r1] = n1;
    }
}

template<int M>
__device__ __forceinline__ void expv(const F2* amp, int q, int lane,
                                     float& fx, float& fy, float& fz) {
    F2 zp = {0.f, 0.f}, zm = {0.f, 0.f}, xp = {0.f, 0.f}, ip = {0.f, 0.f};
#pragma unroll
    for (int r0 = 0; r0 < 16; ++r0) {
        if (r0 & M) continue;
        const int r1 = r0 + M;
        F2 a0 = amp[r0], a1 = amp[r1];
        pk_fma(zp, a0, a0);
        pk_fma(zm, a1, a1);
        pk_fma(xp, a0, a1);
        pk_imacc(ip, a0, a1);
    }
    float zz = (zp.x + zp.y) - (zm.x + zm.y);
    float xr = 2.f * (xp.x + xp.y);
    float xi = 2.f * (ip.x + ip.y);
#pragma unroll
    for (int off = 32; off; off >>= 1) {
        xr += __shfl_xor(xr, off);
        xi += __shfl_xor(xi, off);
        zz += __shfl_xor(zz, off);
    }
    if (lane == q) { fx = xr; fy = xi; fz = zz; }
}

// enumerate j-th pair base r0 with (r0 & M)==0 and (r0 & SB)==hb*SB (4-bit regs)
template<int M, int SB>
__device__ __forceinline__ int r0_of(int j, int hb) {
    int r = hb ? SB : 0, b = 1;
#pragma unroll
    for (int p = 0; p < 4; ++p) {
        const int mm = 1 << p;
        if (mm == M || mm == SB) continue;
        if (j & b) r |= mm;
        b <<= 1;
    }
    return r;
}

// Store one half (8 regs with (r & SB) == HB).
#define ST_T(TP, RP, SB, HB) \
  { _Pragma("unroll") for (int r = 0; r < 16; ++r) { \
      if ((r & (SB)) != (HB)) continue; \
      psi[(TP) ^ RP(r)] = amp[r]; } }
// Load one half in pair order of the next gate (mask M).
#define LD_T(TP, RP, M, SB, HB) \
  { _Pragma("unroll") for (int k = 0; k < 8; ++k) { \
      const int j = k >> 1; \
      const int r0 = r0_of<M, SB>(j, (HB) != 0); \
      const int r = (k & 1) ? (r0 + (M)) : r0; \
      amp[r] = psi[(TP) ^ RP(r)]; } }

// same-wave DS drain (wave-internal transposes; DS ops of one wave are
// processed in order — fence is insurance)
#define WAVE_FENCE asm volatile("s_waitcnt lgkmcnt(0)" ::: "memory")

#define U0P(q, M)               g1q<M, 0,0, 0,0>(amp, cf + (q)*8)
#define FU0(q, MS, M)           do { g1q<M, MS,0,  0,0>(amp, cf + (q)*8); \
                                     g1q<M, MS,MS, 0,0>(amp, cf + 96 + (q)*8); } while(0)
#define FU0_H(q, MS, M, SB, HB) do { g1q<M, SB,HB, MS,0 >(amp, cf + (q)*8); \
                                     g1q<M, SB,HB, MS,MS>(amp, cf + 96 + (q)*8); } while(0)
#define U1P(q, M)               g1q<M, 0,0, 0,0>(amp, cf + 192 + (q)*8)
#define U1P_H(q, M, SB, HB)     g1q<M, SB,HB, 0,0>(amp, cf + 192 + (q)*8)
#define FU1_0()                 do { g1q<8, 4,0, 0,0>(amp, cf + 192); \
                                     g1q<8, 4,4, 0,0>(amp, cf + 288); } while(0)
#define CR1(c, MC, MT)          crx<MC, MT>(amp, F2{cf[296 + (c)*2], cf[296 + (c)*2 + 1]})
#define EXPV(q, M)              expv<M>(amp, q, l, fx, fy, fz)

__global__ __launch_bounds__(256, 8)
void qsim_kernel(const float* __restrict__ sv,      // [B, 4096]
                 const float* __restrict__ cf,      // [320] precomputed coefficients
                 const float* __restrict__ W,       // [10, 36]
                 const float* __restrict__ bvec,    // [10]
                 float* __restrict__ out)           // [B, 10]
{
    __shared__ F2 psi[2048];         // 16 KB split-transpose buffer
    const int t = threadIdx.x;
    const int b = blockIdx.x;
    const int l = t & 63, w = t >> 6;

    F2 amp[16];
    const float* svb = sv + (size_t)b * DIM;
    // layout A: idx = r<<8 | l<<2 | w; pair order for U0P(0, M=8)
#pragma unroll
    for (int k = 0; k < 16; ++k) {
        const int r = (k & 1) ? ((k >> 1) + 8) : (k >> 1);
        amp[r] = make_float2(svb[(r << 8) | (l << 2) | w], 0.f);
    }

    float fx = 0.f, fy = 0.f, fz = 0.f;

    // ---- A {q0:8 q1:4 q2:2 q3:1}: U0(0); [U0;CR0] q=1..3 ----
    U0P(0, 8);
    FU0(1, 8, 4); FU0(2, 4, 2); FU0(3, 2, 1);

    // ---- T1 A->B (internal, del a8, SB=1): halfgate FU0(4,1,4) ----
    {
        const int tpA = tpA1f(l, w), tpB = tpB1f(l, w);
        ST_T(tpA, rpA1, 1, 0); WAVE_FENCE;
        LD_T(tpB, rpB1, 4, 1, 0); WAVE_FENCE;
        ST_T(tpA, rpA1, 1, 1);
        FU0_H(4, 1, 4, 1, 0);
        WAVE_FENCE;
        LD_T(tpB, rpB1, 4, 1, 1);
        FU0_H(4, 1, 4, 1, 1);
    }
    // ---- B {q3:1 q4:4 q5:8 q6:2} ----
    FU0(5, 4, 8); FU0(6, 8, 2);

    // ---- T2 B->C (internal, del a5, SB=2): halfgate FU0(7,2,4) ----
    {
        const int tpB = tpB1f(l, w), tpC = tpC2f(l, w);
        ST_T(tpB, rpB2, 2, 0); WAVE_FENCE;
        LD_T(tpC, rpC2, 4, 2, 0); WAVE_FENCE;
        ST_T(tpB, rpB2, 2, 2);
        FU0_H(7, 2, 4, 2, 0);
        WAVE_FENCE;
        LD_T(tpC, rpC2, 4, 2, 2);
        FU0_H(7, 2, 4, 2, 2);
    }
    // ---- C {q6:2 q7:4 q8:8 q9:1} ----
    FU0(8, 4, 8); FU0(9, 8, 1);

    // ---- T3 C->D (CROSS, del a2, SB=1): halfgate FU0(10,1,2) ----
    __syncthreads();                 // T2 slots not wave-disjoint vs T3 stores
    {
        const int tpC = tpC3f(l, w), tpD = tpD3f(l, w);
        ST_T(tpC, rpC3, 1, 0);
        __syncthreads();
        LD_T(tpD, rpD3, 2, 1, 0);
        __syncthreads();
        ST_T(tpC, rpC3, 1, 1);
        FU0_H(10, 1, 2, 1, 0);
        __syncthreads();
        LD_T(tpD, rpD3, 2, 1, 1);
        FU0_H(10, 1, 2, 1, 1);
    }
    // ---- D {q9:1 q10:2 q11:4 q0:8}: [CR0(11,0);U1(0)]; U1(9..11);
    //      L1 ring (11,0),(10,11),(9,10); expv 10,11 ----
    FU0(11, 2, 4);
    FU1_0();
    U1P(9, 1); U1P(10, 2); U1P(11, 4);
    CR1(11, 4, 8); CR1(10, 2, 4); CR1(9, 1, 2);
    EXPV(10, 2); EXPV(11, 4);

    // ---- T4 D->C' (internal, del a2, SB=1): halfgate U1P(7,4) ----
    // no barrier: T3-LD and T4-ST slots both carry a7a6=wave at f10,f9
    {
        const int tpD = tpD3f(l, w), tpC = tpC4f(l, w);
        ST_T(tpD, rpD3, 1, 0); WAVE_FENCE;
        LD_T(tpC, rpC3, 4, 1, 0); WAVE_FENCE;
        ST_T(tpD, rpD3, 1, 1);
        U1P_H(7, 4, 1, 0);
        WAVE_FENCE;
        LD_T(tpC, rpC3, 4, 1, 1);
        U1P_H(7, 4, 1, 1);
    }
    // ---- C' {q6:2 q7:4 q8:8 q9:1}: U1(6,8); ring (8,9),(7,8),(6,7); expv 7,8,9 ----
    U1P(6, 2); U1P(8, 8);
    CR1(8, 8, 1); CR1(7, 4, 8); CR1(6, 2, 4);
    EXPV(9, 1); EXPV(8, 8); EXPV(7, 4);

    // ---- T5 C'->B' (CROSS, del a5, SB=2): halfgate U1P(3,1) ----
    // no leading barrier: T4-LD and T5-ST slots both carry a7a6=wave at f10,f9
    {
        const int tpC = tpC5f(l, w), tpB = tpB5f(l, w);
        ST_T(tpC, rpC5, 2, 0);
        __syncthreads();
        LD_T(tpB, rpB5, 1, 2, 0);
        __syncthreads();
        ST_T(tpC, rpC5, 2, 2);
        U1P_H(3, 1, 2, 0);
        __syncthreads();
        LD_T(tpB, rpB5, 1, 2, 2);
        U1P_H(3, 1, 2, 2);
        __syncthreads();             // protect cross-wave reads from T6 stores
    }
    // ---- B' {q3:1 q4:4 q5:8 q6:2}: U1(4,5); ring (5,6),(4,5),(3,4); expv 4,5,6 ----
    U1P(4, 4); U1P(5, 8);
    CR1(5, 8, 2); CR1(4, 4, 8); CR1(3, 1, 4);
    EXPV(6, 2); EXPV(5, 8); EXPV(4, 4);

    // ---- T6 B'->A' (internal, del a8, SB=1): halfgate U1P(1,4) ----
    {
        const int tpB = tpB1f(l, w), tpA = tpA1f(l, w);
        ST_T(tpB, rpB1, 1, 0); WAVE_FENCE;
        LD_T(tpA, rpA1, 4, 1, 0); WAVE_FENCE;
        ST_T(tpB, rpB1, 1, 1);
        U1P_H(1, 4, 1, 0);
        WAVE_FENCE;
        LD_T(tpA, rpA1, 4, 1, 1);
        U1P_H(1, 4, 1, 1);
    }
    // ---- A' {q0:8 q1:4 q2:2 q3:1}: U1(2); ring (2,3),(1,2),(0,1); expv 0..3 ----
    U1P(2, 2);
    CR1(2, 2, 1); CR1(1, 4, 2); CR1(0, 8, 4);
    EXPV(3, 1); EXPV(2, 2); EXPV(1, 4); EXPV(0, 8);

    // ---- combine 4 waves' partial features ----
    __syncthreads();                 // psi dead only after all waves' T6 loads
    float* fbuf = (float*)psi;       // [4][36]
    if (l < 12) {
        fbuf[w * 36 + l]      = fx;
        fbuf[w * 36 + 12 + l] = fy;
        fbuf[w * 36 + 24 + l] = fz;
    }
    __syncthreads();
    if (t < 10) {
        float a = bvec[t];
#pragma unroll
        for (int f = 0; f < 36; ++f)
            a += W[t * 36 + f] * (fbuf[f] + fbuf[36 + f] + fbuf[72 + f] + fbuf[108 + f]);
        out[(size_t)b * 10 + t] = a;
    }
}

extern "C" void kernel_launch(void* const* d_in, const int* in_sizes, int n_in,
                              void* d_out, int out_size, void* d_ws, size_t ws_size,
                              hipStream_t stream) {
    const float* sv     = (const float*)d_in[0];
    const float* angles = (const float*)d_in[1];
    const float* W      = (const float*)d_in[2];
    const float* bvec   = (const float*)d_in[3];
    float* out  = (float*)d_out;
    float* coef = (float*)d_ws;      // 320 floats of scratch
    int batch = in_sizes[0] / DIM;   // 2048
    prep_kernel<<<1, 64, 0, stream>>>(angles, coef);
    qsim_kernel<<<batch, 256, 0, stream>>>(sv, coef, W, bvec, out);
}

// Round 5
// 141.210 us; speedup vs baseline: 1.1479x; 1.1479x over previous
//
#include <hip/hip_runtime.h>

#define DIM 4096
using F2 = float2;

// R18 = R17 dataflow (layouts/packings/schedule harness-verified in R16+R17)
// with gate coefficients moved to SGPRs:
//  - all U/M matrices and CRX (cos,sin) are wave-uniform (cf[] at
//    compile-time offsets). readfirstlane -> SGPR; VOP3P primitives take the
//    coefficient operand with an "s" constraint (each pk instr reads exactly
//    one coefficient operand -> respects the 1-scalar-per-VALU-instr rule).
//  - coefficient VGPR liveness ~16 -> 0; fused gates back to single-pass
//    (16 coefficients now cost SGPRs only).
//  - real VGPR need ~= amp(32) + misc(~20) ~= 55. __launch_bounds__(256,6)
//    caps at 85 (wide margin -> no spill cascade, unlike R16/R17). If the
//    allocator lands <=64, HW gives 8 waves/SIMD anyway (launch_bounds caps
//    allocation, not occupancy).
// R16/R17 post-mortem: 4-wave blocks raise residency exactly as designed
// (Occupancy 47->66%) but VGPR caps of 85/64 made the allocator dump amp[]
// to scratch (VGPR=40/32, WRITE_SIZE 106/184 MB) -> 86/95 us. This round
// removes the pressure instead of squeezing the cap.
//
// Address bits: qubit q <-> a[11-q]. Layouts (reg bit value in parens):
//  A : regs a11(8) a10(4) a9(2) a8(1); lanes a7..a2=l5..l0; wave a1a0
//      masks: q0:8 q1:4 q2:2 q3:1
//  B : regs a8(1) a7(4) a6(8) a5(2); lanes a11,a10,a9,a4,a3,a2=l5..l0; wave a1a0
//      masks: q3:1 q4:4 q5:8 q6:2
//  C : regs a5(2) a4(4) a3(8) a2(1); lanes a11..a6=l5..l0; wave a1a0
//      masks: q6:2 q7:4 q8:8 q9:1
//  D : regs a2(1) a1(2) a0(4) a11(8); lanes a10,a9,a8,a5,a4,a3=l5..l0; wave a7a6
//      masks: q9:1 q10:2 q11:4 q0:8
//  C': regs as C; lanes a11,a10,a9,a8,a1,a0=l5..l0; wave a7a6
//  B': = B.   A': = A.
// Transitions: T1 A->B del a8 SB=1 internal; T2 B->C del a5 SB=2 internal;
//  T3 C->D del a2 SB=1 CROSS; T4 D->C' del a2 SB=1 internal;
//  T5 C'->B' del a5 SB=2 CROSS; T6 B'->A' del a8 SB=1 internal.
// Internal transposes: wave bits identical both sides -> same-wave lgkmcnt
// fence only. Cross transposes: real __syncthreads. 8 block barriers total.

// ---- scalar (SGPR) coefficient load: cf values are wave-uniform ----
__device__ __forceinline__ F2 sload2(const float* p) {
    int i0 = __builtin_amdgcn_readfirstlane(__builtin_bit_cast(int, p[0]));
    int i1 = __builtin_amdgcn_readfirstlane(__builtin_bit_cast(int, p[1]));
    F2 r;
    r.x = __builtin_bit_cast(float, i0);
    r.y = __builtin_bit_cast(float, i1);
    return r;
}
#define SL8(p) sload2(p), sload2((p)+2), sload2((p)+4), sload2((p)+6)

// ---- packed fp32 complex primitives (VOP3P), coefficient operand in SGPRs.
// Each instruction reads exactly ONE scalar-pair source (legal: max 1 SGPR
// read per vector instruction). Lane data (a) stays "v".
__device__ __forceinline__ F2 pk_mul_bl(F2 a, F2 u) {   // (a.x*u.x, a.y*u.x)
    F2 d;
    asm("v_pk_mul_f32 %0, %1, %2 op_sel:[0,0] op_sel_hi:[1,0]"
        : "=v"(d) : "v"(a), "s"(u));
    return d;
}
__device__ __forceinline__ void pk_cross(F2& d, F2 a, F2 u) {  // d += (-a.y*u.y, a.x*u.y)
    asm("v_pk_fma_f32 %0, %1, %2, %0 op_sel:[1,1,0] op_sel_hi:[0,1,1] neg_lo:[1,0,0]"
        : "+v"(d) : "v"(a), "s"(u));
}
__device__ __forceinline__ void pk_fma_bl(F2& d, F2 a, F2 u) { // d += (a.x*u.x, a.y*u.x)
    asm("v_pk_fma_f32 %0, %1, %2, %0 op_sel:[0,0,0] op_sel_hi:[1,0,1]"
        : "+v"(d) : "v"(a), "s"(u));
}
__device__ __forceinline__ void pk_swapneg(F2& d, F2 a, F2 cs) { // d += (a.y*cs.y, -a.x*cs.y)
    asm("v_pk_fma_f32 %0, %1, %2, %0 op_sel:[1,1,0] op_sel_hi:[0,1,1] neg_hi:[1,0,0]"
        : "+v"(d) : "v"(a), "s"(cs));
}
// all-VGPR variants (expv: both operands are lane data)
__device__ __forceinline__ void pk_fma(F2& d, F2 a, F2 b) {    // d += a*b
    asm("v_pk_fma_f32 %0, %1, %2, %0" : "+v"(d) : "v"(a), "v"(b));
}
__device__ __forceinline__ void pk_imacc(F2& d, F2 a0, F2 a1) { // d += (a0.x*a1.y, -a0.y*a1.x)
    asm("v_pk_fma_f32 %0, %1, %2, %0 op_sel:[0,1,0] op_sel_hi:[1,0,1] neg_hi:[1,0,0]"
        : "+v"(d) : "v"(a0), "v"(a1));
}
__device__ __forceinline__ F2 pk_cmul(F2 u, F2 a) {
    F2 d = pk_mul_bl(a, u);
    pk_cross(d, a, u);
    return d;
}
__device__ __forceinline__ void pk_cfma(F2& d, F2 u, F2 a) {
    pk_fma_bl(d, a, u);
    pk_cross(d, a, u);
}

__device__ __forceinline__ void build_u(float tx, float ty, float tz, float* u) {
    float sx = sinf(0.5f*tx), cx = cosf(0.5f*tx);
    float sy = sinf(0.5f*ty), cy = cosf(0.5f*ty);
    float sz = sinf(0.5f*tz), cz = cosf(0.5f*tz);
    float A00r = cy*cx, A00i =  sy*sx;     // A = Ry*Rx
    float A01r = -sy*cx, A01i = -cy*sx;
    float A10r =  sy*cx, A10i = -cy*sx;
    float A11r =  cy*cx, A11i = -sy*sx;
    // U = Rz*A: row0 *= (cz - i sz), row1 *= (cz + i sz)   [verified r1/3/5..17]
    u[0] = cz*A00r + sz*A00i;  u[1] = cz*A00i - sz*A00r;
    u[2] = cz*A01r + sz*A01i;  u[3] = cz*A01i - sz*A01r;
    u[4] = cz*A10r - sz*A10i;  u[5] = cz*A10i + sz*A10r;
    u[6] = cz*A11r - sz*A11i;  u[7] = cz*A11i + sz*A11r;
}

// coef layout (floats): [0..95] U0 plain (q*8); [96..191] RX(ang[36+q-1])*U0[q] (q=1..11);
// [192..287] U1 plain; [288..295] U1[0]*RX(ang[47]); [296..319] L1 CRX (cos,sin)[c=0..11]
__global__ void prep_kernel(const float* __restrict__ ang, float* __restrict__ coef) {
    int t = threadIdx.x;
    if (t < 12) {
        float u[8]; build_u(ang[t], ang[12+t], ang[24+t], u);
#pragma unroll
        for (int j = 0; j < 8; ++j) coef[t*8 + j] = u[j];
    } else if (t < 24) {
        int q = t - 12;
        float u[8]; build_u(ang[48+q], ang[60+q], ang[72+q], u);
#pragma unroll
        for (int j = 0; j < 8; ++j) coef[192 + q*8 + j] = u[j];
    } else if (t < 36) {
        int c = t - 24;
        float th = 0.5f * ang[95 - c];     // L1 ring gate (c,c+1) = tape slot 84+(11-c)
        coef[296 + c*2]     = cosf(th);
        coef[296 + c*2 + 1] = sinf(th);
    } else if (t < 47) {
        int q = t - 35;                    // 1..11: M = RX(ang[36+q-1]) * U0[q]
        float u[8]; build_u(ang[q], ang[12+q], ang[24+q], u);
        float c = cosf(0.5f*ang[36+q-1]), s = sinf(0.5f*ang[36+q-1]);
        float m[8];
        m[0] = c*u[0] + s*u[5];  m[1] = c*u[1] - s*u[4];   // M00 = c u00 - i s u10
        m[2] = c*u[2] + s*u[7];  m[3] = c*u[3] - s*u[6];   // M01 = c u01 - i s u11
        m[4] = s*u[1] + c*u[4];  m[5] = -s*u[0] + c*u[5];  // M10 = -i s u00 + c u10
        m[6] = s*u[3] + c*u[6];  m[7] = -s*u[2] + c*u[7];  // M11 = -i s u01 + c u11
#pragma unroll
        for (int j = 0; j < 8; ++j) coef[96 + q*8 + j] = m[j];
    } else if (t == 47) {                  // M = U1[0] * RX(ang[47])  [CR0(11,0) then U1(0)]
        float u[8]; build_u(ang[48], ang[60], ang[72], u);
        float c = cosf(0.5f*ang[47]), s = sinf(0.5f*ang[47]);
        float m[8];
        m[0] = c*u[0] + s*u[3];  m[1] = c*u[1] - s*u[2];   // M00 = c u00 - i s u01
        m[2] = s*u[1] + c*u[2];  m[3] = -s*u[0] + c*u[3];  // M01 = -i s u00 + c u01
        m[4] = c*u[4] + s*u[7];  m[5] = c*u[5] - s*u[6];   // M10 = c u10 - i s u11
        m[6] = s*u[5] + c*u[6];  m[7] = -s*u[4] + c*u[7];  // M11 = -i s u10 + c u11
#pragma unroll
        for (int j = 0; j < 8; ++j) coef[288 + j] = m[j];
    }
}

// ---- register-part (compile-time per unrolled r) of each packing ----
__device__ __forceinline__ int rpA1(int r) {   // T1/T6, A side (a8 deleted = r&1)
    int a11=(r>>3)&1, a10=(r>>2)&1, a9=(r>>1)&1;
    return (a11<<8)|(a10<<7)|(a9<<6)|(a11<<3)|(a10<<2)|(a9<<1)|(a9<<0);
}
__device__ __forceinline__ int rpB1(int r) {   // T1/T6, B side
    int a5=(r>>1)&1, a7=(r>>2)&1, a6=(r>>3)&1;
    return (a7<<5)|(a6<<4)|(a7<<3)|(a6<<2)|(a5<<0);
}
__device__ __forceinline__ int rpB2(int r) {   // T2, B side (a5 deleted = r&2)
    int a8=r&1, a7=(r>>2)&1, a6=(r>>3)&1;
    return (a8<<5)|(a7<<4)|(a6<<3)|(a7<<2)|(a8<<1)|(a6<<0);
}
__device__ __forceinline__ int rpC2(int r) {   // T2, C side
    int a2=r&1, a4=(r>>2)&1, a3=(r>>3)&1;
    return (a3<<3)|(a2<<2)|(a4<<1);
}
__device__ __forceinline__ int rpC3(int r) {   // T3/T4, C/C' side (a2 deleted = r&1)
    int a5=(r>>1)&1, a4=(r>>2)&1, a3=(r>>3)&1;
    return (a5<<4)|(a3<<3)|(a4<<2)|(a5<<0);
}
__device__ __forceinline__ int rpD3(int r) {   // T3/T4, D side
    int a1=(r>>1)&1, a0=(r>>2)&1, a11=(r>>3)&1;
    return (a11<<8)|(a11<<3)|(a1<<1)|((a0^a11)<<0);
}
__device__ __forceinline__ int rpC5(int r) {   // T5, C' side (a5 deleted = r&2)
    int a2=r&1, a4=(r>>2)&1, a3=(r>>3)&1;
    return (a4<<4)|(a3<<3)|(a2<<2)|(a4<<0);
}
__device__ __forceinline__ int rpB5(int r) {   // T5, B' side
    int a8=r&1, a7=(r>>2)&1, a6=(r>>3)&1;
    return (a7<<10)|(a6<<9)|(a8<<5)|(a8<<3);
}

// ---- tile pointers (lane/wave part of each packing); scoped per transpose ----
#define LBITS \
    const int l0=l&1, l1=(l>>1)&1, l2=(l>>2)&1, l3=(l>>3)&1, l4=(l>>4)&1, \
              l5=(l>>5)&1, w0=w&1, w1=(w>>1)&1; \
    (void)l0;(void)l1;(void)l2;(void)l3;(void)l4;(void)l5;(void)w0;(void)w1;

__device__ __forceinline__ int tpA1f(int l, int w) { LBITS
    return (w1<<10)|(w0<<9)|(l5<<5)|(l4<<4)|((l1^l5)<<3)|((l0^l4)<<2)|(l2<<1)|(l3<<0); }
__device__ __forceinline__ int tpB1f(int l, int w) { LBITS
    return (w1<<10)|(w0<<9)|(l5<<8)|(l4<<7)|(l3<<6)|((l1^l5)<<3)|((l0^l4)<<2)|((l2^l3)<<1)|(l3<<0); }
__device__ __forceinline__ int tpC2f(int l, int w) { LBITS
    return (w1<<10)|(w0<<9)|(l5<<8)|(l4<<7)|(l3<<6)|(l2<<5)|(l1<<4)|((l5^l0)<<3)|((l4^l1)<<2)|((l3^l2)<<1)|((l0^l3)<<0); }
__device__ __forceinline__ int tpC3f(int l, int w) { LBITS
    return (l1<<10)|(l0<<9)|(l5<<8)|(l4<<7)|(l3<<6)|(l2<<5)|((l5^l4)<<3)|(l3<<2)|((w1^l2)<<1)|((w0^l5)<<0); }
__device__ __forceinline__ int tpD3f(int l, int w) { LBITS
    return (w1<<10)|(w0<<9)|(l5<<7)|(l4<<6)|(l3<<5)|(l2<<4)|((l0^l5)<<3)|((l1^l4)<<2)|(l3<<1)|(l2<<0); }
__device__ __forceinline__ int tpC4f(int l, int w) { LBITS
    return (w1<<10)|(w0<<9)|(l5<<8)|(l4<<7)|(l3<<6)|(l2<<5)|((l5^l4)<<3)|(l3<<2)|((l1^l2)<<1)|((l0^l5)<<0); }
__device__ __forceinline__ int tpC5f(int l, int w) { LBITS
    return (w1<<10)|(w0<<9)|(l5<<8)|(l4<<7)|(l3<<6)|(l2<<5)|((l5^l2)<<3)|(l4<<2)|((l1^l3)<<1)|(l0<<0); }
__device__ __forceinline__ int tpB5f(int l, int w) { LBITS
    return (l5<<8)|(l4<<7)|(l3<<6)|(l2<<4)|((l1^l5)<<3)|((l0^l4)<<2)|((w1^l3)<<1)|((w0^l2)<<0); }

// Plain 1q gate over subset {r0: (r0&M)==0, (S1==0 || (r0&S1)==H1)};
// coefficients live in SGPRs (by-value F2 from sload2).
template<int M, int S1, int H1>
__device__ __forceinline__ void g1q(F2* amp, F2 u00, F2 u01, F2 u10, F2 u11) {
#pragma unroll
    for (int r0 = 0; r0 < 16; ++r0) {
        if (r0 & M) continue;
        if (S1 != 0 && (r0 & S1) != H1) continue;
        const int r1 = r0 + M;
        F2 a0 = amp[r0], a1 = amp[r1];
        F2 n0 = pk_cmul(u00, a0); pk_cfma(n0, u01, a1);
        F2 n1 = pk_cmul(u10, a0); pk_cfma(n1, u11, a1);
        amp[r0] = n0; amp[r1] = n1;
    }
}

// Fused gate: matrix selected per pair by compile-time control bit MSEL.
// Both matrices in SGPRs -> no VGPR cost for holding 16 coefficients.
template<int MSEL, int M, int S1, int H1>
__device__ __forceinline__ void fg1q(F2* amp, F2 a00, F2 a01, F2 a10, F2 a11,
                                     F2 b00, F2 b01, F2 b10, F2 b11) {
#pragma unroll
    for (int r0 = 0; r0 < 16; ++r0) {
        if (r0 & M) continue;
        if (S1 != 0 && (r0 & S1) != H1) continue;
        const int r1 = r0 + M;
        const bool sel = (r0 & MSEL) != 0;           // compile-time
        F2 u00 = sel ? b00 : a00, u01 = sel ? b01 : a01;
        F2 u10 = sel ? b10 : a10, u11 = sel ? b11 : a11;
        F2 a0 = amp[r0], a1 = amp[r1];
        F2 n0 = pk_cmul(u00, a0); pk_cfma(n0, u01, a1);
        F2 n1 = pk_cmul(u10, a0); pk_cfma(n1, u11, a1);
        amp[r0] = n0; amp[r1] = n1;
    }
}

template<int MC, int MT>
__device__ __forceinline__ void crx(F2* amp, F2 cs) {   // cs in SGPRs
#pragma unroll
    for (int r0 = 0; r0 < 16; ++r0) {
        if (!(r0 & MC) || (r0 & MT)) continue;
        const int r1 = r0 + MT;
        F2 a0 = amp[r0], a1 = amp[r1];
        F2 n0 = pk_mul_bl(a0, cs); pk_swapneg(n0, a1, cs);
        F2 n1 = pk_mul_bl(a1, cs); pk_swapneg(n1, a0, cs);
        amp[r0] = n0; amp[r1] = n1;
    }
}

template<int M>
__device__ __forceinline__ void expv(const F2* amp, int q, int lane,
                                     float& fx, float& fy, float& fz) {
    F2 zp = {0.f, 0.f}, zm = {0.f, 0.f}, xp = {0.f, 0.f}, ip = {0.f, 0.f};
#pragma unroll
    for (int r0 = 0; r0 < 16; ++r0) {
        if (r0 & M) continue;
        const int r1 = r0 + M;
        F2 a0 = amp[r0], a1 = amp[r1];
        pk_fma(zp, a0, a0);
        pk_fma(zm, a1, a1);
        pk_fma(xp, a0, a1);
        pk_imacc(ip, a0, a1);
    }
    float zz = (zp.x + zp.y) - (zm.x + zm.y);
    float xr = 2.f * (xp.x + xp.y);
    float xi = 2.f * (ip.x + ip.y);
#pragma unroll
    for (int off = 32; off; off >>= 1) {
        xr += __shfl_xor(xr, off);
        xi += __shfl_xor(xi, off);
        zz += __shfl_xor(zz, off);
    }
    if (lane == q) { fx = xr; fy = xi; fz = zz; }
}

// enumerate j-th pair base r0 with (r0 & M)==0 and (r0 & SB)==hb*SB (4-bit regs)
template<int M, int SB>
__device__ __forceinline__ int r0_of(int j, int hb) {
    int r = hb ? SB : 0, b = 1;
#pragma unroll
    for (int p = 0; p < 4; ++p) {
        const int mm = 1 << p;
        if (mm == M || mm == SB) continue;
        if (j & b) r |= mm;
        b <<= 1;
    }
    return r;
}

// Store one half (8 regs with (r & SB) == HB).
#define ST_T(TP, RP, SB, HB) \
  { _Pragma("unroll") for (int r = 0; r < 16; ++r) { \
      if ((r & (SB)) != (HB)) continue; \
      psi[(TP) ^ RP(r)] = amp[r]; } }
// Load one half in pair order of the next gate (mask M).
#define LD_T(TP, RP, M, SB, HB) \
  { _Pragma("unroll") for (int k = 0; k < 8; ++k) { \
      const int j = k >> 1; \
      const int r0 = r0_of<M, SB>(j, (HB) != 0); \
      const int r = (k & 1) ? (r0 + (M)) : r0; \
      amp[r] = psi[(TP) ^ RP(r)]; } }

// same-wave DS drain (wave-internal transposes; DS ops of one wave are
// processed in order — fence is insurance)
#define WAVE_FENCE asm volatile("s_waitcnt lgkmcnt(0)" ::: "memory")

#define U0P(q, M)               g1q<M, 0, 0>(amp, SL8(cf + (q)*8))
#define FU0(q, MS, M)           fg1q<MS, M, 0, 0>(amp, SL8(cf + (q)*8), SL8(cf + 96 + (q)*8))
#define FU0_H(q, MS, M, SB, HB) fg1q<MS, M, SB, HB>(amp, SL8(cf + (q)*8), SL8(cf + 96 + (q)*8))
#define U1P(q, M)               g1q<M, 0, 0>(amp, SL8(cf + 192 + (q)*8))
#define U1P_H(q, M, SB, HB)     g1q<M, SB, HB>(amp, SL8(cf + 192 + (q)*8))
#define FU1_0()                 fg1q<4, 8, 0, 0>(amp, SL8(cf + 192), SL8(cf + 288))
#define CR1(c, MC, MT)          crx<MC, MT>(amp, sload2(cf + 296 + (c)*2))
#define EXPV(q, M)              expv<M>(amp, q, l, fx, fy, fz)

__global__ __launch_bounds__(256, 6)
void qsim_kernel(const float* __restrict__ sv,      // [B, 4096]
                 const float* __restrict__ cf,      // [320] precomputed coefficients
                 const float* __restrict__ W,       // [10, 36]
                 const float* __restrict__ bvec,    // [10]
                 float* __restrict__ out)           // [B, 10]
{
    __shared__ F2 psi[2048];         // 16 KB split-transpose buffer
    const int t = threadIdx.x;
    const int b = blockIdx.x;
    const int l = t & 63, w = t >> 6;

    F2 amp[16];
    const float* svb = sv + (size_t)b * DIM;
    // layout A: idx = r<<8 | l<<2 | w; pair order for U0P(0, M=8)
#pragma unroll
    for (int k = 0; k < 16; ++k) {
        const int r = (k & 1) ? ((k >> 1) + 8) : (k >> 1);
        amp[r] = make_float2(svb[(r << 8) | (l << 2) | w], 0.f);
    }

    float fx = 0.f, fy = 0.f, fz = 0.f;

    // ---- A {q0:8 q1:4 q2:2 q3:1}: U0(0); [U0;CR0] q=1..3 ----
    U0P(0, 8);
    FU0(1, 8, 4); FU0(2, 4, 2); FU0(3, 2, 1);

    // ---- T1 A->B (internal, del a8, SB=1): halfgate FU0(4,1,4) ----
    {
        const int tpA = tpA1f(l, w), tpB = tpB1f(l, w);
        ST_T(tpA, rpA1, 1, 0); WAVE_FENCE;
        LD_T(tpB, rpB1, 4, 1, 0); WAVE_FENCE;
        ST_T(tpA, rpA1, 1, 1);
        FU0_H(4, 1, 4, 1, 0);
        WAVE_FENCE;
        LD_T(tpB, rpB1, 4, 1, 1);
        FU0_H(4, 1, 4, 1, 1);
    }
    // ---- B {q3:1 q4:4 q5:8 q6:2} ----
    FU0(5, 4, 8); FU0(6, 8, 2);

    // ---- T2 B->C (internal, del a5, SB=2): halfgate FU0(7,2,4) ----
    {
        const int tpB = tpB1f(l, w), tpC = tpC2f(l, w);
        ST_T(tpB, rpB2, 2, 0); WAVE_FENCE;
        LD_T(tpC, rpC2, 4, 2, 0); WAVE_FENCE;
        ST_T(tpB, rpB2, 2, 2);
        FU0_H(7, 2, 4, 2, 0);
        WAVE_FENCE;
        LD_T(tpC, rpC2, 4, 2, 2);
        FU0_H(7, 2, 4, 2, 2);
    }
    // ---- C {q6:2 q7:4 q8:8 q9:1} ----
    FU0(8, 4, 8); FU0(9, 8, 1);

    // ---- T3 C->D (CROSS, del a2, SB=1): halfgate FU0(10,1,2) ----
    __syncthreads();                 // T2 slots not wave-disjoint vs T3 stores
    {
        const int tpC = tpC3f(l, w), tpD = tpD3f(l, w);
        ST_T(tpC, rpC3, 1, 0);
        __syncthreads();
        LD_T(tpD, rpD3, 2, 1, 0);
        __syncthreads();
        ST_T(tpC, rpC3, 1, 1);
        FU0_H(10, 1, 2, 1, 0);
        __syncthreads();
        LD_T(tpD, rpD3, 2, 1, 1);
        FU0_H(10, 1, 2, 1, 1);
    }
    // ---- D {q9:1 q10:2 q11:4 q0:8}: [CR0(11,0);U1(0)]; U1(9..11);
    //      L1 ring (11,0),(10,11),(9,10); expv 10,11 ----
    FU0(11, 2, 4);
    FU1_0();
    U1P(9, 1); U1P(10, 2); U1P(11, 4);
    CR1(11, 4, 8); CR1(10, 2, 4); CR1(9, 1, 2);
    EXPV(10, 2); EXPV(11, 4);

    // ---- T4 D->C' (internal, del a2, SB=1): halfgate U1P(7,4) ----
    // no barrier: T3-LD and T4-ST slots both carry a7a6=wave at f10,f9
    {
        const int tpD = tpD3f(l, w), tpC = tpC4f(l, w);
        ST_T(tpD, rpD3, 1, 0); WAVE_FENCE;
        LD_T(tpC, rpC3, 4, 1, 0); WAVE_FENCE;
        ST_T(tpD, rpD3, 1, 1);
        U1P_H(7, 4, 1, 0);
        WAVE_FENCE;
        LD_T(tpC, rpC3, 4, 1, 1);
        U1P_H(7, 4, 1, 1);
    }
    // ---- C' {q6:2 q7:4 q8:8 q9:1}: U1(6,8); ring (8,9),(7,8),(6,7); expv 7,8,9 ----
    U1P(6, 2); U1P(8, 8);
    CR1(8, 8, 1); CR1(7, 4, 8); CR1(6, 2, 4);
    EXPV(9, 1); EXPV(8, 8); EXPV(7, 4);

    // ---- T5 C'->B' (CROSS, del a5, SB=2): halfgate U1P(3,1) ----
    // no leading barrier: T4-LD and T5-ST slots both carry a7a6=wave at f10,f9
    {
        const int tpC = tpC5f(l, w), tpB = tpB5f(l, w);
        ST_T(tpC, rpC5, 2, 0);
        __syncthreads();
        LD_T(tpB, rpB5, 1, 2, 0);
        __syncthreads();
        ST_T(tpC, rpC5, 2, 2);
        U1P_H(3, 1, 2, 0);
        __syncthreads();
        LD_T(tpB, rpB5, 1, 2, 2);
        U1P_H(3, 1, 2, 2);
        __syncthreads();             // protect cross-wave reads from T6 stores
    }
    // ---- B' {q3:1 q4:4 q5:8 q6:2}: U1(4,5); ring (5,6),(4,5),(3,4); expv 4,5,6 ----
    U1P(4, 4); U1P(5, 8);
    CR1(5, 8, 2); CR1(4, 4, 8); CR1(3, 1, 4);
    EXPV(6, 2); EXPV(5, 8); EXPV(4, 4);

    // ---- T6 B'->A' (internal, del a8, SB=1): halfgate U1P(1,4) ----
    {
        const int tpB = tpB1f(l, w), tpA = tpA1f(l, w);
        ST_T(tpB, rpB1, 1, 0); WAVE_FENCE;
        LD_T(tpA, rpA1, 4, 1, 0); WAVE_FENCE;
        ST_T(tpB, rpB1, 1, 1);
        U1P_H(1, 4, 1, 0);
        WAVE_FENCE;
        LD_T(tpA, rpA1, 4, 1, 1);
        U1P_H(1, 4, 1, 1);
    }
    // ---- A' {q0:8 q1:4 q2:2 q3:1}: U1(2); ring (2,3),(1,2),(0,1); expv 0..3 ----
    U1P(2, 2);
    CR1(2, 2, 1); CR1(1, 4, 2); CR1(0, 8, 4);
    EXPV(3, 1); EXPV(2, 2); EXPV(1, 4); EXPV(0, 8);

    // ---- combine 4 waves' partial features ----
    __syncthreads();                 // psi dead only after all waves' T6 loads
    float* fbuf = (float*)psi;       // [4][36]
    if (l < 12) {
        fbuf[w * 36 + l]      = fx;
        fbuf[w * 36 + 12 + l] = fy;
        fbuf[w * 36 + 24 + l] = fz;
    }
    __syncthreads();
    if (t < 10) {
        float a = bvec[t];
#pragma unroll
        for (int f = 0; f < 36; ++f)
            a += W[t * 36 + f] * (fbuf[f] + fbuf[36 + f] + fbuf[72 + f] + fbuf[108 + f]);
        out[(size_t)b * 10 + t] = a;
    }
}

extern "C" void kernel_launch(void* const* d_in, const int* in_sizes, int n_in,
                              void* d_out, int out_size, void* d_ws, size_t ws_size,
                              hipStream_t stream) {
    const float* sv     = (const float*)d_in[0];
    const float* angles = (const float*)d_in[1];
    const float* W      = (const float*)d_in[2];
    const float* bvec   = (const float*)d_in[3];
    float* out  = (float*)d_out;
    float* coef = (float*)d_ws;      // 320 floats of scratch
    int batch = in_sizes[0] / DIM;   // 2048
    prep_kernel<<<1, 64, 0, stream>>>(angles, coef);
    qsim_kernel<<<batch, 256, 0, stream>>>(sv, coef, W, bvec, out);
}

// Round 6
// 134.537 us; speedup vs baseline: 1.2049x; 1.0496x over previous
//
#include <hip/hip_runtime.h>

#define DIM 4096
using F2 = float2;

// R19 = R18 byte-identical EXCEPT __launch_bounds__(256, 1).
// Spill forensics across R16-R18: need(~52) < budget(64..85) yet allocator
// produced VGPR=32..40 + 95-184 MB scratch traffic. Common factor: min_waves
// >= 6 makes the backend target occupancy ABOVE the minimum (pressure
// heuristic), capping VGPRs below real need -> catastrophic amp[] spill.
// min_waves=1 (R13/R15) never spilled. launch_bounds caps allocation, not
// achieved occupancy: natural allocation <= 64 VGPRs -> HW grants 8
// waves/SIMD automatically (occupancy steps at 64/128/256).
// Structure (harness-verified R16/R17/R18): 4 waves/state, amp[16]/lane,
// 6 transposes (4 wave-internal, 2 cross), SGPR gate coefficients.
//
// Address bits: qubit q <-> a[11-q]. Layouts (reg bit value in parens):
//  A : regs a11(8) a10(4) a9(2) a8(1); lanes a7..a2=l5..l0; wave a1a0
//      masks: q0:8 q1:4 q2:2 q3:1
//  B : regs a8(1) a7(4) a6(8) a5(2); lanes a11,a10,a9,a4,a3,a2=l5..l0; wave a1a0
//      masks: q3:1 q4:4 q5:8 q6:2
//  C : regs a5(2) a4(4) a3(8) a2(1); lanes a11..a6=l5..l0; wave a1a0
//      masks: q6:2 q7:4 q8:8 q9:1
//  D : regs a2(1) a1(2) a0(4) a11(8); lanes a10,a9,a8,a5,a4,a3=l5..l0; wave a7a6
//      masks: q9:1 q10:2 q11:4 q0:8
//  C': regs as C; lanes a11,a10,a9,a8,a1,a0=l5..l0; wave a7a6
//  B': = B.   A': = A.
// Transitions: T1 A->B del a8 SB=1 internal; T2 B->C del a5 SB=2 internal;
//  T3 C->D del a2 SB=1 CROSS; T4 D->C' del a2 SB=1 internal;
//  T5 C'->B' del a5 SB=2 CROSS; T6 B'->A' del a8 SB=1 internal.
// Internal transposes: wave bits identical both sides -> same-wave lgkmcnt
// fence only. Cross transposes: real __syncthreads. 8 block barriers total.

// ---- scalar (SGPR) coefficient load: cf values are wave-uniform ----
__device__ __forceinline__ F2 sload2(const float* p) {
    int i0 = __builtin_amdgcn_readfirstlane(__builtin_bit_cast(int, p[0]));
    int i1 = __builtin_amdgcn_readfirstlane(__builtin_bit_cast(int, p[1]));
    F2 r;
    r.x = __builtin_bit_cast(float, i0);
    r.y = __builtin_bit_cast(float, i1);
    return r;
}
#define SL8(p) sload2(p), sload2((p)+2), sload2((p)+4), sload2((p)+6)

// ---- packed fp32 complex primitives (VOP3P), coefficient operand in SGPRs.
// Each instruction reads exactly ONE scalar-pair source (legal: max 1 SGPR
// read per vector instruction). Lane data (a) stays "v".
__device__ __forceinline__ F2 pk_mul_bl(F2 a, F2 u) {   // (a.x*u.x, a.y*u.x)
    F2 d;
    asm("v_pk_mul_f32 %0, %1, %2 op_sel:[0,0] op_sel_hi:[1,0]"
        : "=v"(d) : "v"(a), "s"(u));
    return d;
}
__device__ __forceinline__ void pk_cross(F2& d, F2 a, F2 u) {  // d += (-a.y*u.y, a.x*u.y)
    asm("v_pk_fma_f32 %0, %1, %2, %0 op_sel:[1,1,0] op_sel_hi:[0,1,1] neg_lo:[1,0,0]"
        : "+v"(d) : "v"(a), "s"(u));
}
__device__ __forceinline__ void pk_fma_bl(F2& d, F2 a, F2 u) { // d += (a.x*u.x, a.y*u.x)
    asm("v_pk_fma_f32 %0, %1, %2, %0 op_sel:[0,0,0] op_sel_hi:[1,0,1]"
        : "+v"(d) : "v"(a), "s"(u));
}
__device__ __forceinline__ void pk_swapneg(F2& d, F2 a, F2 cs) { // d += (a.y*cs.y, -a.x*cs.y)
    asm("v_pk_fma_f32 %0, %1, %2, %0 op_sel:[1,1,0] op_sel_hi:[0,1,1] neg_hi:[1,0,0]"
        : "+v"(d) : "v"(a), "s"(cs));
}
// all-VGPR variants (expv: both operands are lane data)
__device__ __forceinline__ void pk_fma(F2& d, F2 a, F2 b) {    // d += a*b
    asm("v_pk_fma_f32 %0, %1, %2, %0" : "+v"(d) : "v"(a), "v"(b));
}
__device__ __forceinline__ void pk_imacc(F2& d, F2 a0, F2 a1) { // d += (a0.x*a1.y, -a0.y*a1.x)
    asm("v_pk_fma_f32 %0, %1, %2, %0 op_sel:[0,1,0] op_sel_hi:[1,0,1] neg_hi:[1,0,0]"
        : "+v"(d) : "v"(a0), "v"(a1));
}
__device__ __forceinline__ F2 pk_cmul(F2 u, F2 a) {
    F2 d = pk_mul_bl(a, u);
    pk_cross(d, a, u);
    return d;
}
__device__ __forceinline__ void pk_cfma(F2& d, F2 u, F2 a) {
    pk_fma_bl(d, a, u);
    pk_cross(d, a, u);
}

__device__ __forceinline__ void build_u(float tx, float ty, float tz, float* u) {
    float sx = sinf(0.5f*tx), cx = cosf(0.5f*tx);
    float sy = sinf(0.5f*ty), cy = cosf(0.5f*ty);
    float sz = sinf(0.5f*tz), cz = cosf(0.5f*tz);
    float A00r = cy*cx, A00i =  sy*sx;     // A = Ry*Rx
    float A01r = -sy*cx, A01i = -cy*sx;
    float A10r =  sy*cx, A10i = -cy*sx;
    float A11r =  cy*cx, A11i = -sy*sx;
    // U = Rz*A: row0 *= (cz - i sz), row1 *= (cz + i sz)   [verified r1/3/5..18]
    u[0] = cz*A00r + sz*A00i;  u[1] = cz*A00i - sz*A00r;
    u[2] = cz*A01r + sz*A01i;  u[3] = cz*A01i - sz*A01r;
    u[4] = cz*A10r - sz*A10i;  u[5] = cz*A10i + sz*A10r;
    u[6] = cz*A11r - sz*A11i;  u[7] = cz*A11i + sz*A11r;
}

// coef layout (floats): [0..95] U0 plain (q*8); [96..191] RX(ang[36+q-1])*U0[q] (q=1..11);
// [192..287] U1 plain; [288..295] U1[0]*RX(ang[47]); [296..319] L1 CRX (cos,sin)[c=0..11]
__global__ void prep_kernel(const float* __restrict__ ang, float* __restrict__ coef) {
    int t = threadIdx.x;
    if (t < 12) {
        float u[8]; build_u(ang[t], ang[12+t], ang[24+t], u);
#pragma unroll
        for (int j = 0; j < 8; ++j) coef[t*8 + j] = u[j];
    } else if (t < 24) {
        int q = t - 12;
        float u[8]; build_u(ang[48+q], ang[60+q], ang[72+q], u);
#pragma unroll
        for (int j = 0; j < 8; ++j) coef[192 + q*8 + j] = u[j];
    } else if (t < 36) {
        int c = t - 24;
        float th = 0.5f * ang[95 - c];     // L1 ring gate (c,c+1) = tape slot 84+(11-c)
        coef[296 + c*2]     = cosf(th);
        coef[296 + c*2 + 1] = sinf(th);
    } else if (t < 47) {
        int q = t - 35;                    // 1..11: M = RX(ang[36+q-1]) * U0[q]
        float u[8]; build_u(ang[q], ang[12+q], ang[24+q], u);
        float c = cosf(0.5f*ang[36+q-1]), s = sinf(0.5f*ang[36+q-1]);
        float m[8];
        m[0] = c*u[0] + s*u[5];  m[1] = c*u[1] - s*u[4];   // M00 = c u00 - i s u10
        m[2] = c*u[2] + s*u[7];  m[3] = c*u[3] - s*u[6];   // M01 = c u01 - i s u11
        m[4] = s*u[1] + c*u[4];  m[5] = -s*u[0] + c*u[5];  // M10 = -i s u00 + c u10
        m[6] = s*u[3] + c*u[6];  m[7] = -s*u[2] + c*u[7];  // M11 = -i s u01 + c u11
#pragma unroll
        for (int j = 0; j < 8; ++j) coef[96 + q*8 + j] = m[j];
    } else if (t == 47) {                  // M = U1[0] * RX(ang[47])  [CR0(11,0) then U1(0)]
        float u[8]; build_u(ang[48], ang[60], ang[72], u);
        float c = cosf(0.5f*ang[47]), s = sinf(0.5f*ang[47]);
        float m[8];
        m[0] = c*u[0] + s*u[3];  m[1] = c*u[1] - s*u[2];   // M00 = c u00 - i s u01
        m[2] = s*u[1] + c*u[2];  m[3] = -s*u[0] + c*u[3];  // M01 = -i s u00 + c u01
        m[4] = c*u[4] + s*u[7];  m[5] = c*u[5] - s*u[6];   // M10 = c u10 - i s u11
        m[6] = s*u[5] + c*u[6];  m[7] = -s*u[4] + c*u[7];  // M11 = -i s u10 + c u11
#pragma unroll
        for (int j = 0; j < 8; ++j) coef[288 + j] = m[j];
    }
}

// ---- register-part (compile-time per unrolled r) of each packing ----
__device__ __forceinline__ int rpA1(int r) {   // T1/T6, A side (a8 deleted = r&1)
    int a11=(r>>3)&1, a10=(r>>2)&1, a9=(r>>1)&1;
    return (a11<<8)|(a10<<7)|(a9<<6)|(a11<<3)|(a10<<2)|(a9<<1)|(a9<<0);
}
__device__ __forceinline__ int rpB1(int r) {   // T1/T6, B side
    int a5=(r>>1)&1, a7=(r>>2)&1, a6=(r>>3)&1;
    return (a7<<5)|(a6<<4)|(a7<<3)|(a6<<2)|(a5<<0);
}
__device__ __forceinline__ int rpB2(int r) {   // T2, B side (a5 deleted = r&2)
    int a8=r&1, a7=(r>>2)&1, a6=(r>>3)&1;
    return (a8<<5)|(a7<<4)|(a6<<3)|(a7<<2)|(a8<<1)|(a6<<0);
}
__device__ __forceinline__ int rpC2(int r) {   // T2, C side
    int a2=r&1, a4=(r>>2)&1, a3=(r>>3)&1;
    return (a3<<3)|(a2<<2)|(a4<<1);
}
__device__ __forceinline__ int rpC3(int r) {   // T3/T4, C/C' side (a2 deleted = r&1)
    int a5=(r>>1)&1, a4=(r>>2)&1, a3=(r>>3)&1;
    return (a5<<4)|(a3<<3)|(a4<<2)|(a5<<0);
}
__device__ __forceinline__ int rpD3(int r) {   // T3/T4, D side
    int a1=(r>>1)&1, a0=(r>>2)&1, a11=(r>>3)&1;
    return (a11<<8)|(a11<<3)|(a1<<1)|((a0^a11)<<0);
}
__device__ __forceinline__ int rpC5(int r) {   // T5, C' side (a5 deleted = r&2)
    int a2=r&1, a4=(r>>2)&1, a3=(r>>3)&1;
    return (a4<<4)|(a3<<3)|(a2<<2)|(a4<<0);
}
__device__ __forceinline__ int rpB5(int r) {   // T5, B' side
    int a8=r&1, a7=(r>>2)&1, a6=(r>>3)&1;
    return (a7<<10)|(a6<<9)|(a8<<5)|(a8<<3);
}

// ---- tile pointers (lane/wave part of each packing); scoped per transpose ----
#define LBITS \
    const int l0=l&1, l1=(l>>1)&1, l2=(l>>2)&1, l3=(l>>3)&1, l4=(l>>4)&1, \
              l5=(l>>5)&1, w0=w&1, w1=(w>>1)&1; \
    (void)l0;(void)l1;(void)l2;(void)l3;(void)l4;(void)l5;(void)w0;(void)w1;

__device__ __forceinline__ int tpA1f(int l, int w) { LBITS
    return (w1<<10)|(w0<<9)|(l5<<5)|(l4<<4)|((l1^l5)<<3)|((l0^l4)<<2)|(l2<<1)|(l3<<0); }
__device__ __forceinline__ int tpB1f(int l, int w) { LBITS
    return (w1<<10)|(w0<<9)|(l5<<8)|(l4<<7)|(l3<<6)|((l1^l5)<<3)|((l0^l4)<<2)|((l2^l3)<<1)|(l3<<0); }
__device__ __forceinline__ int tpC2f(int l, int w) { LBITS
    return (w1<<10)|(w0<<9)|(l5<<8)|(l4<<7)|(l3<<6)|(l2<<5)|(l1<<4)|((l5^l0)<<3)|((l4^l1)<<2)|((l3^l2)<<1)|((l0^l3)<<0); }
__device__ __forceinline__ int tpC3f(int l, int w) { LBITS
    return (l1<<10)|(l0<<9)|(l5<<8)|(l4<<7)|(l3<<6)|(l2<<5)|((l5^l4)<<3)|(l3<<2)|((w1^l2)<<1)|((w0^l5)<<0); }
__device__ __forceinline__ int tpD3f(int l, int w) { LBITS
    return (w1<<10)|(w0<<9)|(l5<<7)|(l4<<6)|(l3<<5)|(l2<<4)|((l0^l5)<<3)|((l1^l4)<<2)|(l3<<1)|(l2<<0); }
__device__ __forceinline__ int tpC4f(int l, int w) { LBITS
    return (w1<<10)|(w0<<9)|(l5<<8)|(l4<<7)|(l3<<6)|(l2<<5)|((l5^l4)<<3)|(l3<<2)|((l1^l2)<<1)|((l0^l5)<<0); }
__device__ __forceinline__ int tpC5f(int l, int w) { LBITS
    return (w1<<10)|(w0<<9)|(l5<<8)|(l4<<7)|(l3<<6)|(l2<<5)|((l5^l2)<<3)|(l4<<2)|((l1^l3)<<1)|(l0<<0); }
__device__ __forceinline__ int tpB5f(int l, int w) { LBITS
    return (l5<<8)|(l4<<7)|(l3<<6)|(l2<<4)|((l1^l5)<<3)|((l0^l4)<<2)|((w1^l3)<<1)|((w0^l2)<<0); }

// Plain 1q gate over subset {r0: (r0&M)==0, (S1==0 || (r0&S1)==H1)};
// coefficients live in SGPRs (by-value F2 from sload2).
template<int M, int S1, int H1>
__device__ __forceinline__ void g1q(F2* amp, F2 u00, F2 u01, F2 u10, F2 u11) {
#pragma unroll
    for (int r0 = 0; r0 < 16; ++r0) {
        if (r0 & M) continue;
        if (S1 != 0 && (r0 & S1) != H1) continue;
        const int r1 = r0 + M;
        F2 a0 = amp[r0], a1 = amp[r1];
        F2 n0 = pk_cmul(u00, a0); pk_cfma(n0, u01, a1);
        F2 n1 = pk_cmul(u10, a0); pk_cfma(n1, u11, a1);
        amp[r0] = n0; amp[r1] = n1;
    }
}

// Fused gate: matrix selected per pair by compile-time control bit MSEL.
// Both matrices in SGPRs -> no VGPR cost for holding 16 coefficients.
template<int MSEL, int M, int S1, int H1>
__device__ __forceinline__ void fg1q(F2* amp, F2 a00, F2 a01, F2 a10, F2 a11,
                                     F2 b00, F2 b01, F2 b10, F2 b11) {
#pragma unroll
    for (int r0 = 0; r0 < 16; ++r0) {
        if (r0 & M) continue;
        if (S1 != 0 && (r0 & S1) != H1) continue;
        const int r1 = r0 + M;
        const bool sel = (r0 & MSEL) != 0;           // compile-time
        F2 u00 = sel ? b00 : a00, u01 = sel ? b01 : a01;
        F2 u10 = sel ? b10 : a10, u11 = sel ? b11 : a11;
        F2 a0 = amp[r0], a1 = amp[r1];
        F2 n0 = pk_cmul(u00, a0); pk_cfma(n0, u01, a1);
        F2 n1 = pk_cmul(u10, a0); pk_cfma(n1, u11, a1);
        amp[r0] = n0; amp[r1] = n1;
    }
}

template<int MC, int MT>
__device__ __forceinline__ void crx(F2* amp, F2 cs) {   // cs in SGPRs
#pragma unroll
    for (int r0 = 0; r0 < 16; ++r0) {
        if (!(r0 & MC) || (r0 & MT)) continue;
        const int r1 = r0 + MT;
        F2 a0 = amp[r0], a1 = amp[r1];
        F2 n0 = pk_mul_bl(a0, cs); pk_swapneg(n0, a1, cs);
        F2 n1 = pk_mul_bl(a1, cs); pk_swapneg(n1, a0, cs);
        amp[r0] = n0; amp[r1] = n1;
    }
}

template<int M>
__device__ __forceinline__ void expv(const F2* amp, int q, int lane,
                                     float& fx, float& fy, float& fz) {
    F2 zp = {0.f, 0.f}, zm = {0.f, 0.f}, xp = {0.f, 0.f}, ip = {0.f, 0.f};
#pragma unroll
    for (int r0 = 0; r0 < 16; ++r0) {
        if (r0 & M) continue;
        const int r1 = r0 + M;
        F2 a0 = amp[r0], a1 = amp[r1];
        pk_fma(zp, a0, a0);
        pk_fma(zm, a1, a1);
        pk_fma(xp, a0, a1);
        pk_imacc(ip, a0, a1);
    }
    float zz = (zp.x + zp.y) - (zm.x + zm.y);
    float xr = 2.f * (xp.x + xp.y);
    float xi = 2.f * (ip.x + ip.y);
#pragma unroll
    for (int off = 32; off; off >>= 1) {
        xr += __shfl_xor(xr, off);
        xi += __shfl_xor(xi, off);
        zz += __shfl_xor(zz, off);
    }
    if (lane == q) { fx = xr; fy = xi; fz = zz; }
}

// enumerate j-th pair base r0 with (r0 & M)==0 and (r0 & SB)==hb*SB (4-bit regs)
template<int M, int SB>
__device__ __forceinline__ int r0_of(int j, int hb) {
    int r = hb ? SB : 0, b = 1;
#pragma unroll
    for (int p = 0; p < 4; ++p) {
        const int mm = 1 << p;
        if (mm == M || mm == SB) continue;
        if (j & b) r |= mm;
        b <<= 1;
    }
    return r;
}

// Store one half (8 regs with (r & SB) == HB).
#define ST_T(TP, RP, SB, HB) \
  { _Pragma("unroll") for (int r = 0; r < 16; ++r) { \
      if ((r & (SB)) != (HB)) continue; \
      psi[(TP) ^ RP(r)] = amp[r]; } }
// Load one half in pair order of the next gate (mask M).
#define LD_T(TP, RP, M, SB, HB) \
  { _Pragma("unroll") for (int k = 0; k < 8; ++k) { \
      const int j = k >> 1; \
      const int r0 = r0_of<M, SB>(j, (HB) != 0); \
      const int r = (k & 1) ? (r0 + (M)) : r0; \
      amp[r] = psi[(TP) ^ RP(r)]; } }

// same-wave DS drain (wave-internal transposes; DS ops of one wave are
// processed in order — fence is insurance)
#define WAVE_FENCE asm volatile("s_waitcnt lgkmcnt(0)" ::: "memory")

#define U0P(q, M)               g1q<M, 0, 0>(amp, SL8(cf + (q)*8))
#define FU0(q, MS, M)           fg1q<MS, M, 0, 0>(amp, SL8(cf + (q)*8), SL8(cf + 96 + (q)*8))
#define FU0_H(q, MS, M, SB, HB) fg1q<MS, M, SB, HB>(amp, SL8(cf + (q)*8), SL8(cf + 96 + (q)*8))
#define U1P(q, M)               g1q<M, 0, 0>(amp, SL8(cf + 192 + (q)*8))
#define U1P_H(q, M, SB, HB)     g1q<M, SB, HB>(amp, SL8(cf + 192 + (q)*8))
#define FU1_0()                 fg1q<4, 8, 0, 0>(amp, SL8(cf + 192), SL8(cf + 288))
#define CR1(c, MC, MT)          crx<MC, MT>(amp, sload2(cf + 296 + (c)*2))
#define EXPV(q, M)              expv<M>(amp, q, l, fx, fy, fz)

__global__ __launch_bounds__(256, 1)
void qsim_kernel(const float* __restrict__ sv,      // [B, 4096]
                 const float* __restrict__ cf,      // [320] precomputed coefficients
                 const float* __restrict__ W,       // [10, 36]
                 const float* __restrict__ bvec,    // [10]
                 float* __restrict__ out)           // [B, 10]
{
    __shared__ F2 psi[2048];         // 16 KB split-transpose buffer
    const int t = threadIdx.x;
    const int b = blockIdx.x;
    const int l = t & 63, w = t >> 6;

    F2 amp[16];
    const float* svb = sv + (size_t)b * DIM;
    // layout A: idx = r<<8 | l<<2 | w; pair order for U0P(0, M=8)
#pragma unroll
    for (int k = 0; k < 16; ++k) {
        const int r = (k & 1) ? ((k >> 1) + 8) : (k >> 1);
        amp[r] = make_float2(svb[(r << 8) | (l << 2) | w], 0.f);
    }

    float fx = 0.f, fy = 0.f, fz = 0.f;

    // ---- A {q0:8 q1:4 q2:2 q3:1}: U0(0); [U0;CR0] q=1..3 ----
    U0P(0, 8);
    FU0(1, 8, 4); FU0(2, 4, 2); FU0(3, 2, 1);

    // ---- T1 A->B (internal, del a8, SB=1): halfgate FU0(4,1,4) ----
    {
        const int tpA = tpA1f(l, w), tpB = tpB1f(l, w);
        ST_T(tpA, rpA1, 1, 0); WAVE_FENCE;
        LD_T(tpB, rpB1, 4, 1, 0); WAVE_FENCE;
        ST_T(tpA, rpA1, 1, 1);
        FU0_H(4, 1, 4, 1, 0);
        WAVE_FENCE;
        LD_T(tpB, rpB1, 4, 1, 1);
        FU0_H(4, 1, 4, 1, 1);
    }
    // ---- B {q3:1 q4:4 q5:8 q6:2} ----
    FU0(5, 4, 8); FU0(6, 8, 2);

    // ---- T2 B->C (internal, del a5, SB=2): halfgate FU0(7,2,4) ----
    {
        const int tpB = tpB1f(l, w), tpC = tpC2f(l, w);
        ST_T(tpB, rpB2, 2, 0); WAVE_FENCE;
        LD_T(tpC, rpC2, 4, 2, 0); WAVE_FENCE;
        ST_T(tpB, rpB2, 2, 2);
        FU0_H(7, 2, 4, 2, 0);
        WAVE_FENCE;
        LD_T(tpC, rpC2, 4, 2, 2);
        FU0_H(7, 2, 4, 2, 2);
    }
    // ---- C {q6:2 q7:4 q8:8 q9:1} ----
    FU0(8, 4, 8); FU0(9, 8, 1);

    // ---- T3 C->D (CROSS, del a2, SB=1): halfgate FU0(10,1,2) ----
    __syncthreads();                 // T2 slots not wave-disjoint vs T3 stores
    {
        const int tpC = tpC3f(l, w), tpD = tpD3f(l, w);
        ST_T(tpC, rpC3, 1, 0);
        __syncthreads();
        LD_T(tpD, rpD3, 2, 1, 0);
        __syncthreads();
        ST_T(tpC, rpC3, 1, 1);
        FU0_H(10, 1, 2, 1, 0);
        __syncthreads();
        LD_T(tpD, rpD3, 2, 1, 1);
        FU0_H(10, 1, 2, 1, 1);
    }
    // ---- D {q9:1 q10:2 q11:4 q0:8}: [CR0(11,0);U1(0)]; U1(9..11);
    //      L1 ring (11,0),(10,11),(9,10); expv 10,11 ----
    FU0(11, 2, 4);
    FU1_0();
    U1P(9, 1); U1P(10, 2); U1P(11, 4);
    CR1(11, 4, 8); CR1(10, 2, 4); CR1(9, 1, 2);
    EXPV(10, 2); EXPV(11, 4);

    // ---- T4 D->C' (internal, del a2, SB=1): halfgate U1P(7,4) ----
    // no barrier: T3-LD and T4-ST slots both carry a7a6=wave at f10,f9
    {
        const int tpD = tpD3f(l, w), tpC = tpC4f(l, w);
        ST_T(tpD, rpD3, 1, 0); WAVE_FENCE;
        LD_T(tpC, rpC3, 4, 1, 0); WAVE_FENCE;
        ST_T(tpD, rpD3, 1, 1);
        U1P_H(7, 4, 1, 0);
        WAVE_FENCE;
        LD_T(tpC, rpC3, 4, 1, 1);
        U1P_H(7, 4, 1, 1);
    }
    // ---- C' {q6:2 q7:4 q8:8 q9:1}: U1(6,8); ring (8,9),(7,8),(6,7); expv 7,8,9 ----
    U1P(6, 2); U1P(8, 8);
    CR1(8, 8, 1); CR1(7, 4, 8); CR1(6, 2, 4);
    EXPV(9, 1); EXPV(8, 8); EXPV(7, 4);

    // ---- T5 C'->B' (CROSS, del a5, SB=2): halfgate U1P(3,1) ----
    // no leading barrier: T4-LD and T5-ST slots both carry a7a6=wave at f10,f9
    {
        const int tpC = tpC5f(l, w), tpB = tpB5f(l, w);
        ST_T(tpC, rpC5, 2, 0);
        __syncthreads();
        LD_T(tpB, rpB5, 1, 2, 0);
        __syncthreads();
        ST_T(tpC, rpC5, 2, 2);
        U1P_H(3, 1, 2, 0);
        __syncthreads();
        LD_T(tpB, rpB5, 1, 2, 2);
        U1P_H(3, 1, 2, 2);
        __syncthreads();             // protect cross-wave reads from T6 stores
    }
    // ---- B' {q3:1 q4:4 q5:8 q6:2}: U1(4,5); ring (5,6),(4,5),(3,4); expv 4,5,6 ----
    U1P(4, 4); U1P(5, 8);
    CR1(5, 8, 2); CR1(4, 4, 8); CR1(3, 1, 4);
    EXPV(6, 2); EXPV(5, 8); EXPV(4, 4);

    // ---- T6 B'->A' (internal, del a8, SB=1): halfgate U1P(1,4) ----
    {
        const int tpB = tpB1f(l, w), tpA = tpA1f(l, w);
        ST_T(tpB, rpB1, 1, 0); WAVE_FENCE;
        LD_T(tpA, rpA1, 4, 1, 0); WAVE_FENCE;
        ST_T(tpB, rpB1, 1, 1);
        U1P_H(1, 4, 1, 0);
        WAVE_FENCE;
        LD_T(tpA, rpA1, 4, 1, 1);
        U1P_H(1, 4, 1, 1);
    }
    // ---- A' {q0:8 q1:4 q2:2 q3:1}: U1(2); ring (2,3),(1,2),(0,1); expv 0..3 ----
    U1P(2, 2);
    CR1(2, 2, 1); CR1(1, 4, 2); CR1(0, 8, 4);
    EXPV(3, 1); EXPV(2, 2); EXPV(1, 4); EXPV(0, 8);

    // ---- combine 4 waves' partial features ----
    __syncthreads();                 // psi dead only after all waves' T6 loads
    float* fbuf = (float*)psi;       // [4][36]
    if (l < 12) {
        fbuf[w * 36 + l]      = fx;
        fbuf[w * 36 + 12 + l] = fy;
        fbuf[w * 36 + 24 + l] = fz;
    }
    __syncthreads();
    if (t < 10) {
        float a = bvec[t];
#pragma unroll
        for (int f = 0; f < 36; ++f)
            a += W[t * 36 + f] * (fbuf[f] + fbuf[36 + f] + fbuf[72 + f] + fbuf[108 + f]);
        out[(size_t)b * 10 + t] = a;
    }
}

extern "C" void kernel_launch(void* const* d_in, const int* in_sizes, int n_in,
                              void* d_out, int out_size, void* d_ws, size_t ws_size,
                              hipStream_t stream) {
    const float* sv     = (const float*)d_in[0];
    const float* angles = (const float*)d_in[1];
    const float* W      = (const float*)d_in[2];
    const float* bvec   = (const float*)d_in[3];
    float* out  = (float*)d_out;
    float* coef = (float*)d_ws;      // 320 floats of scratch
    int batch = in_sizes[0] / DIM;   // 2048
    prep_kernel<<<1, 64, 0, stream>>>(angles, coef);
    qsim_kernel<<<batch, 256, 0, stream>>>(sv, coef, W, bvec, out);
}

// Round 7
// 133.925 us; speedup vs baseline: 1.2104x; 1.0046x over previous
//
#include <hip/hip_runtime.h>

#define DIM 4096
using F2 = float2;
using F8 = __attribute__((ext_vector_type(8))) float;
using F2V = __attribute__((ext_vector_type(2))) float;

// R20 = R19 (qsim 64.3 us, VGPR 64, no spill) with two changes:
//  (1) coefficients via TRUE scalar loads: one s_load_dwordx8 per gate matrix
//      (s_load_dwordx2 per CRX) into SGPRs, inline asm with embedded
//      s_waitcnt. Replaces ~330 global_load + ~330 v_readfirstlane per wave
//      (~12% of the 5.7k instr/wave measured via VALUBusy arithmetic) with
//      ~38 SMEM ops. VOP3P "s"-constraint consumption already HW-proven
//      (R18/R19 passed). Halfgate matrices hoisted, loaded once per use-site.
//  (2) WAVE_FENCE (lgkmcnt(0)) removed from wave-internal transposes: LDS
//      processes a wave's DS ops in order, so same-wave ST->LD RAW and
//      LD->ST WAR need no drain; compiler auto-waits the loaded registers.
//      Cross-wave transposes (T3/T5) keep their __syncthreads structure.
// Dataflow/layouts/packings byte-identical to R19 (harness-verified 4x).
//
// Address bits: qubit q <-> a[11-q]. Layouts (reg bit value in parens):
//  A : regs a11(8) a10(4) a9(2) a8(1); lanes a7..a2=l5..l0; wave a1a0
//      masks: q0:8 q1:4 q2:2 q3:1
//  B : regs a8(1) a7(4) a6(8) a5(2); lanes a11,a10,a9,a4,a3,a2=l5..l0; wave a1a0
//      masks: q3:1 q4:4 q5:8 q6:2
//  C : regs a5(2) a4(4) a3(8) a2(1); lanes a11..a6=l5..l0; wave a1a0
//      masks: q6:2 q7:4 q8:8 q9:1
//  D : regs a2(1) a1(2) a0(4) a11(8); lanes a10,a9,a8,a5,a4,a3=l5..l0; wave a7a6
//      masks: q9:1 q10:2 q11:4 q0:8
//  C': regs as C; lanes a11,a10,a9,a8,a1,a0=l5..l0; wave a7a6
//  B': = B.   A': = A.
// Transitions: T1 A->B del a8 SB=1 internal; T2 B->C del a5 SB=2 internal;
//  T3 C->D del a2 SB=1 CROSS; T4 D->C' del a2 SB=1 internal;
//  T5 C'->B' del a5 SB=2 CROSS; T6 B'->A' del a8 SB=1 internal.

// ---- scalar coefficient loads (SMEM; K$ invalidated at dispatch start so
// prep_kernel's stores are visible) ----
__device__ __forceinline__ F8 sld8(const float* p) {
    F8 r;
    asm volatile("s_load_dwordx8 %0, %1, 0x0\n\ts_waitcnt lgkmcnt(0)"
                 : "=s"(r) : "s"(p));
    return r;
}
__device__ __forceinline__ void sld16(const float* pa, const float* pb, F8& a, F8& b) {
    asm volatile("s_load_dwordx8 %0, %2, 0x0\n\t"
                 "s_load_dwordx8 %1, %3, 0x0\n\t"
                 "s_waitcnt lgkmcnt(0)"
                 : "=&s"(a), "=&s"(b) : "s"(pa), "s"(pb));
}
__device__ __forceinline__ F2 sld2(const float* p) {
    F2V r;
    asm volatile("s_load_dwordx2 %0, %1, 0x0\n\ts_waitcnt lgkmcnt(0)"
                 : "=s"(r) : "s"(p));
    return F2{r[0], r[1]};
}

// ---- packed fp32 complex primitives (VOP3P), coefficient operand in SGPRs.
// Each instruction reads exactly ONE scalar-pair source. Lane data stays "v".
__device__ __forceinline__ F2 pk_mul_bl(F2 a, F2 u) {   // (a.x*u.x, a.y*u.x)
    F2 d;
    asm("v_pk_mul_f32 %0, %1, %2 op_sel:[0,0] op_sel_hi:[1,0]"
        : "=v"(d) : "v"(a), "s"(u));
    return d;
}
__device__ __forceinline__ void pk_cross(F2& d, F2 a, F2 u) {  // d += (-a.y*u.y, a.x*u.y)
    asm("v_pk_fma_f32 %0, %1, %2, %0 op_sel:[1,1,0] op_sel_hi:[0,1,1] neg_lo:[1,0,0]"
        : "+v"(d) : "v"(a), "s"(u));
}
__device__ __forceinline__ void pk_fma_bl(F2& d, F2 a, F2 u) { // d += (a.x*u.x, a.y*u.x)
    asm("v_pk_fma_f32 %0, %1, %2, %0 op_sel:[0,0,0] op_sel_hi:[1,0,1]"
        : "+v"(d) : "v"(a), "s"(u));
}
__device__ __forceinline__ void pk_swapneg(F2& d, F2 a, F2 cs) { // d += (a.y*cs.y, -a.x*cs.y)
    asm("v_pk_fma_f32 %0, %1, %2, %0 op_sel:[1,1,0] op_sel_hi:[0,1,1] neg_hi:[1,0,0]"
        : "+v"(d) : "v"(a), "s"(cs));
}
// all-VGPR variants (expv: both operands are lane data)
__device__ __forceinline__ void pk_fma(F2& d, F2 a, F2 b) {    // d += a*b
    asm("v_pk_fma_f32 %0, %1, %2, %0" : "+v"(d) : "v"(a), "v"(b));
}
__device__ __forceinline__ void pk_imacc(F2& d, F2 a0, F2 a1) { // d += (a0.x*a1.y, -a0.y*a1.x)
    asm("v_pk_fma_f32 %0, %1, %2, %0 op_sel:[0,1,0] op_sel_hi:[1,0,1] neg_hi:[1,0,0]"
        : "+v"(d) : "v"(a0), "v"(a1));
}
__device__ __forceinline__ F2 pk_cmul(F2 u, F2 a) {
    F2 d = pk_mul_bl(a, u);
    pk_cross(d, a, u);
    return d;
}
__device__ __forceinline__ void pk_cfma(F2& d, F2 u, F2 a) {
    pk_fma_bl(d, a, u);
    pk_cross(d, a, u);
}

__device__ __forceinline__ void build_u(float tx, float ty, float tz, float* u) {
    float sx = sinf(0.5f*tx), cx = cosf(0.5f*tx);
    float sy = sinf(0.5f*ty), cy = cosf(0.5f*ty);
    float sz = sinf(0.5f*tz), cz = cosf(0.5f*tz);
    float A00r = cy*cx, A00i =  sy*sx;     // A = Ry*Rx
    float A01r = -sy*cx, A01i = -cy*sx;
    float A10r =  sy*cx, A10i = -cy*sx;
    float A11r =  cy*cx, A11i = -sy*sx;
    // U = Rz*A: row0 *= (cz - i sz), row1 *= (cz + i sz)   [verified r1/3/5..19]
    u[0] = cz*A00r + sz*A00i;  u[1] = cz*A00i - sz*A00r;
    u[2] = cz*A01r + sz*A01i;  u[3] = cz*A01i - sz*A01r;
    u[4] = cz*A10r - sz*A10i;  u[5] = cz*A10i + sz*A10r;
    u[6] = cz*A11r - sz*A11i;  u[7] = cz*A11i + sz*A11r;
}

// coef layout (floats): [0..95] U0 plain (q*8); [96..191] RX(ang[36+q-1])*U0[q] (q=1..11);
// [192..287] U1 plain; [288..295] U1[0]*RX(ang[47]); [296..319] L1 CRX (cos,sin)[c=0..11]
__global__ void prep_kernel(const float* __restrict__ ang, float* __restrict__ coef) {
    int t = threadIdx.x;
    if (t < 12) {
        float u[8]; build_u(ang[t], ang[12+t], ang[24+t], u);
#pragma unroll
        for (int j = 0; j < 8; ++j) coef[t*8 + j] = u[j];
    } else if (t < 24) {
        int q = t - 12;
        float u[8]; build_u(ang[48+q], ang[60+q], ang[72+q], u);
#pragma unroll
        for (int j = 0; j < 8; ++j) coef[192 + q*8 + j] = u[j];
    } else if (t < 36) {
        int c = t - 24;
        float th = 0.5f * ang[95 - c];     // L1 ring gate (c,c+1) = tape slot 84+(11-c)
        coef[296 + c*2]     = cosf(th);
        coef[296 + c*2 + 1] = sinf(th);
    } else if (t < 47) {
        int q = t - 35;                    // 1..11: M = RX(ang[36+q-1]) * U0[q]
        float u[8]; build_u(ang[q], ang[12+q], ang[24+q], u);
        float c = cosf(0.5f*ang[36+q-1]), s = sinf(0.5f*ang[36+q-1]);
        float m[8];
        m[0] = c*u[0] + s*u[5];  m[1] = c*u[1] - s*u[4];   // M00 = c u00 - i s u10
        m[2] = c*u[2] + s*u[7];  m[3] = c*u[3] - s*u[6];   // M01 = c u01 - i s u11
        m[4] = s*u[1] + c*u[4];  m[5] = -s*u[0] + c*u[5];  // M10 = -i s u00 + c u10
        m[6] = s*u[3] + c*u[6];  m[7] = -s*u[2] + c*u[7];  // M11 = -i s u01 + c u11
#pragma unroll
        for (int j = 0; j < 8; ++j) coef[96 + q*8 + j] = m[j];
    } else if (t == 47) {                  // M = U1[0] * RX(ang[47])  [CR0(11,0) then U1(0)]
        float u[8]; build_u(ang[48], ang[60], ang[72], u);
        float c = cosf(0.5f*ang[47]), s = sinf(0.5f*ang[47]);
        float m[8];
        m[0] = c*u[0] + s*u[3];  m[1] = c*u[1] - s*u[2];   // M00 = c u00 - i s u01
        m[2] = s*u[1] + c*u[2];  m[3] = -s*u[0] + c*u[3];  // M01 = -i s u00 + c u01
        m[4] = c*u[4] + s*u[7];  m[5] = c*u[5] - s*u[6];   // M10 = c u10 - i s u11
        m[6] = s*u[5] + c*u[6];  m[7] = -s*u[4] + c*u[7];  // M11 = -i s u10 + c u11
#pragma unroll
        for (int j = 0; j < 8; ++j) coef[288 + j] = m[j];
    }
}

// ---- register-part (compile-time per unrolled r) of each packing ----
__device__ __forceinline__ int rpA1(int r) {   // T1/T6, A side (a8 deleted = r&1)
    int a11=(r>>3)&1, a10=(r>>2)&1, a9=(r>>1)&1;
    return (a11<<8)|(a10<<7)|(a9<<6)|(a11<<3)|(a10<<2)|(a9<<1)|(a9<<0);
}
__device__ __forceinline__ int rpB1(int r) {   // T1/T6, B side
    int a5=(r>>1)&1, a7=(r>>2)&1, a6=(r>>3)&1;
    return (a7<<5)|(a6<<4)|(a7<<3)|(a6<<2)|(a5<<0);
}
__device__ __forceinline__ int rpB2(int r) {   // T2, B side (a5 deleted = r&2)
    int a8=r&1, a7=(r>>2)&1, a6=(r>>3)&1;
    return (a8<<5)|(a7<<4)|(a6<<3)|(a7<<2)|(a8<<1)|(a6<<0);
}
__device__ __forceinline__ int rpC2(int r) {   // T2, C side
    int a2=r&1, a4=(r>>2)&1, a3=(r>>3)&1;
    return (a3<<3)|(a2<<2)|(a4<<1);
}
__device__ __forceinline__ int rpC3(int r) {   // T3/T4, C/C' side (a2 deleted = r&1)
    int a5=(r>>1)&1, a4=(r>>2)&1, a3=(r>>3)&1;
    return (a5<<4)|(a3<<3)|(a4<<2)|(a5<<0);
}
__device__ __forceinline__ int rpD3(int r) {   // T3/T4, D side
    int a1=(r>>1)&1, a0=(r>>2)&1, a11=(r>>3)&1;
    return (a11<<8)|(a11<<3)|(a1<<1)|((a0^a11)<<0);
}
__device__ __forceinline__ int rpC5(int r) {   // T5, C' side (a5 deleted = r&2)
    int a2=r&1, a4=(r>>2)&1, a3=(r>>3)&1;
    return (a4<<4)|(a3<<3)|(a2<<2)|(a4<<0);
}
__device__ __forceinline__ int rpB5(int r) {   // T5, B' side
    int a8=r&1, a7=(r>>2)&1, a6=(r>>3)&1;
    return (a7<<10)|(a6<<9)|(a8<<5)|(a8<<3);
}

// ---- tile pointers (lane/wave part of each packing); scoped per transpose ----
#define LBITS \
    const int l0=l&1, l1=(l>>1)&1, l2=(l>>2)&1, l3=(l>>3)&1, l4=(l>>4)&1, \
              l5=(l>>5)&1, w0=w&1, w1=(w>>1)&1; \
    (void)l0;(void)l1;(void)l2;(void)l3;(void)l4;(void)l5;(void)w0;(void)w1;

__device__ __forceinline__ int tpA1f(int l, int w) { LBITS
    return (w1<<10)|(w0<<9)|(l5<<5)|(l4<<4)|((l1^l5)<<3)|((l0^l4)<<2)|(l2<<1)|(l3<<0); }
__device__ __forceinline__ int tpB1f(int l, int w) { LBITS
    return (w1<<10)|(w0<<9)|(l5<<8)|(l4<<7)|(l3<<6)|((l1^l5)<<3)|((l0^l4)<<2)|((l2^l3)<<1)|(l3<<0); }
__device__ __forceinline__ int tpC2f(int l, int w) { LBITS
    return (w1<<10)|(w0<<9)|(l5<<8)|(l4<<7)|(l3<<6)|(l2<<5)|(l1<<4)|((l5^l0)<<3)|((l4^l1)<<2)|((l3^l2)<<1)|((l0^l3)<<0); }
__device__ __forceinline__ int tpC3f(int l, int w) { LBITS
    return (l1<<10)|(l0<<9)|(l5<<8)|(l4<<7)|(l3<<6)|(l2<<5)|((l5^l4)<<3)|(l3<<2)|((w1^l2)<<1)|((w0^l5)<<0); }
__device__ __forceinline__ int tpD3f(int l, int w) { LBITS
    return (w1<<10)|(w0<<9)|(l5<<7)|(l4<<6)|(l3<<5)|(l2<<4)|((l0^l5)<<3)|((l1^l4)<<2)|(l3<<1)|(l2<<0); }
__device__ __forceinline__ int tpC4f(int l, int w) { LBITS
    return (w1<<10)|(w0<<9)|(l5<<8)|(l4<<7)|(l3<<6)|(l2<<5)|((l5^l4)<<3)|(l3<<2)|((l1^l2)<<1)|((l0^l5)<<0); }
__device__ __forceinline__ int tpC5f(int l, int w) { LBITS
    return (w1<<10)|(w0<<9)|(l5<<8)|(l4<<7)|(l3<<6)|(l2<<5)|((l5^l2)<<3)|(l4<<2)|((l1^l3)<<1)|(l0<<0); }
__device__ __forceinline__ int tpB5f(int l, int w) { LBITS
    return (l5<<8)|(l4<<7)|(l3<<6)|(l2<<4)|((l1^l5)<<3)|((l0^l4)<<2)|((w1^l3)<<1)|((w0^l2)<<0); }

// Plain 1q gate over subset {r0: (r0&M)==0, (S1==0 || (r0&S1)==H1)};
// coefficients in SGPRs.
template<int M, int S1, int H1>
__device__ __forceinline__ void g1q(F2* amp, F2 u00, F2 u01, F2 u10, F2 u11) {
#pragma unroll
    for (int r0 = 0; r0 < 16; ++r0) {
        if (r0 & M) continue;
        if (S1 != 0 && (r0 & S1) != H1) continue;
        const int r1 = r0 + M;
        F2 a0 = amp[r0], a1 = amp[r1];
        F2 n0 = pk_cmul(u00, a0); pk_cfma(n0, u01, a1);
        F2 n1 = pk_cmul(u10, a0); pk_cfma(n1, u11, a1);
        amp[r0] = n0; amp[r1] = n1;
    }
}
template<int M, int S1, int H1>
__device__ __forceinline__ void g1qF(F2* amp, F8 u) {
    g1q<M, S1, H1>(amp, F2{u[0],u[1]}, F2{u[2],u[3]}, F2{u[4],u[5]}, F2{u[6],u[7]});
}

// Fused gate: matrix selected per pair by compile-time control bit MSEL.
template<int MSEL, int M, int S1, int H1>
__device__ __forceinline__ void fg1q(F2* amp, F2 a00, F2 a01, F2 a10, F2 a11,
                                     F2 b00, F2 b01, F2 b10, F2 b11) {
#pragma unroll
    for (int r0 = 0; r0 < 16; ++r0) {
        if (r0 & M) continue;
        if (S1 != 0 && (r0 & S1) != H1) continue;
        const int r1 = r0 + M;
        const bool sel = (r0 & MSEL) != 0;           // compile-time
        F2 u00 = sel ? b00 : a00, u01 = sel ? b01 : a01;
        F2 u10 = sel ? b10 : a10, u11 = sel ? b11 : a11;
        F2 a0 = amp[r0], a1 = amp[r1];
        F2 n0 = pk_cmul(u00, a0); pk_cfma(n0, u01, a1);
        F2 n1 = pk_cmul(u10, a0); pk_cfma(n1, u11, a1);
        amp[r0] = n0; amp[r1] = n1;
    }
}
template<int MSEL, int M, int S1, int H1>
__device__ __forceinline__ void fg1qF(F2* amp, F8 a, F8 b) {
    fg1q<MSEL, M, S1, H1>(amp,
        F2{a[0],a[1]}, F2{a[2],a[3]}, F2{a[4],a[5]}, F2{a[6],a[7]},
        F2{b[0],b[1]}, F2{b[2],b[3]}, F2{b[4],b[5]}, F2{b[6],b[7]});
}

template<int MC, int MT>
__device__ __forceinline__ void crx(F2* amp, F2 cs) {   // cs in SGPRs
#pragma unroll
    for (int r0 = 0; r0 < 16; ++r0) {
        if (!(r0 & MC) || (r0 & MT)) continue;
        const int r1 = r0 + MT;
        F2 a0 = amp[r0], a1 = amp[r1];
        F2 n0 = pk_mul_bl(a0, cs); pk_swapneg(n0, a1, cs);
        F2 n1 = pk_mul_bl(a1, cs); pk_swapneg(n1, a0, cs);
        amp[r0] = n0; amp[r1] = n1;
    }
}

template<int M>
__device__ __forceinline__ void expv(const F2* amp, int q, int lane,
                                     float& fx, float& fy, float& fz) {
    F2 zp = {0.f, 0.f}, zm = {0.f, 0.f}, xp = {0.f, 0.f}, ip = {0.f, 0.f};
#pragma unroll
    for (int r0 = 0; r0 < 16; ++r0) {
        if (r0 & M) continue;
        const int r1 = r0 + M;
        F2 a0 = amp[r0], a1 = amp[r1];
        pk_fma(zp, a0, a0);
        pk_fma(zm, a1, a1);
        pk_fma(xp, a0, a1);
        pk_imacc(ip, a0, a1);
    }
    float zz = (zp.x + zp.y) - (zm.x + zm.y);
    float xr = 2.f * (xp.x + xp.y);
    float xi = 2.f * (ip.x + ip.y);
#pragma unroll
    for (int off = 32; off; off >>= 1) {
        xr += __shfl_xor(xr, off);
        xi += __shfl_xor(xi, off);
        zz += __shfl_xor(zz, off);
    }
    if (lane == q) { fx = xr; fy = xi; fz = zz; }
}

// enumerate j-th pair base r0 with (r0 & M)==0 and (r0 & SB)==hb*SB (4-bit regs)
template<int M, int SB>
__device__ __forceinline__ int r0_of(int j, int hb) {
    int r = hb ? SB : 0, b = 1;
#pragma unroll
    for (int p = 0; p < 4; ++p) {
        const int mm = 1 << p;
        if (mm == M || mm == SB) continue;
        if (j & b) r |= mm;
        b <<= 1;
    }
    return r;
}

// Store one half (8 regs with (r & SB) == HB).
#define ST_T(TP, RP, SB, HB) \
  { _Pragma("unroll") for (int r = 0; r < 16; ++r) { \
      if ((r & (SB)) != (HB)) continue; \
      psi[(TP) ^ RP(r)] = amp[r]; } }
// Load one half in pair order of the next gate (mask M).
#define LD_T(TP, RP, M, SB, HB) \
  { _Pragma("unroll") for (int k = 0; k < 8; ++k) { \
      const int j = k >> 1; \
      const int r0 = r0_of<M, SB>(j, (HB) != 0); \
      const int r = (k & 1) ? (r0 + (M)) : r0; \
      amp[r] = psi[(TP) ^ RP(r)]; } }

#define U0P(q, M)    g1qF<M, 0, 0>(amp, sld8(cf + (q)*8))
#define FU0(q, MS, M) do { F8 ua_, ub_; sld16(cf + (q)*8, cf + 96 + (q)*8, ua_, ub_); \
                           fg1qF<MS, M, 0, 0>(amp, ua_, ub_); } while(0)
#define U1P(q, M)    g1qF<M, 0, 0>(amp, sld8(cf + 192 + (q)*8))
#define FU1_0()      do { F8 ua_, ub_; sld16(cf + 192, cf + 288, ua_, ub_); \
                          fg1qF<4, 8, 0, 0>(amp, ua_, ub_); } while(0)
#define CR1(c, MC, MT) crx<MC, MT>(amp, sld2(cf + 296 + (c)*2))
#define EXPV(q, M)   expv<M>(amp, q, l, fx, fy, fz)

__global__ __launch_bounds__(256, 1)
void qsim_kernel(const float* __restrict__ sv,      // [B, 4096]
                 const float* __restrict__ cf,      // [320] precomputed coefficients
                 const float* __restrict__ W,       // [10, 36]
                 const float* __restrict__ bvec,    // [10]
                 float* __restrict__ out)           // [B, 10]
{
    __shared__ F2 psi[2048];         // 16 KB split-transpose buffer
    const int t = threadIdx.x;
    const int b = blockIdx.x;
    const int l = t & 63, w = t >> 6;

    F2 amp[16];
    const float* svb = sv + (size_t)b * DIM;
    // layout A: idx = r<<8 | l<<2 | w; pair order for U0P(0, M=8)
#pragma unroll
    for (int k = 0; k < 16; ++k) {
        const int r = (k & 1) ? ((k >> 1) + 8) : (k >> 1);
        amp[r] = make_float2(svb[(r << 8) | (l << 2) | w], 0.f);
    }

    float fx = 0.f, fy = 0.f, fz = 0.f;

    // ---- A {q0:8 q1:4 q2:2 q3:1}: U0(0); [U0;CR0] q=1..3 ----
    U0P(0, 8);
    FU0(1, 8, 4); FU0(2, 4, 2); FU0(3, 2, 1);

    // ---- T1 A->B (internal, del a8, SB=1): halfgate FU0(4,1,4) ----
    // no fences: same-wave DS ops are processed in order; compiler waits
    // the loaded registers before the gate uses them.
    {
        F8 ua, ub; sld16(cf + 4*8, cf + 96 + 4*8, ua, ub);
        const int tpA = tpA1f(l, w), tpB = tpB1f(l, w);
        ST_T(tpA, rpA1, 1, 0);
        LD_T(tpB, rpB1, 4, 1, 0);
        ST_T(tpA, rpA1, 1, 1);
        fg1qF<1, 4, 1, 0>(amp, ua, ub);
        LD_T(tpB, rpB1, 4, 1, 1);
        fg1qF<1, 4, 1, 1>(amp, ua, ub);
    }
    // ---- B {q3:1 q4:4 q5:8 q6:2} ----
    FU0(5, 4, 8); FU0(6, 8, 2);

    // ---- T2 B->C (internal, del a5, SB=2): halfgate FU0(7,2,4) ----
    {
        F8 ua, ub; sld16(cf + 7*8, cf + 96 + 7*8, ua, ub);
        const int tpB = tpB1f(l, w), tpC = tpC2f(l, w);
        ST_T(tpB, rpB2, 2, 0);
        LD_T(tpC, rpC2, 4, 2, 0);
        ST_T(tpB, rpB2, 2, 2);
        fg1qF<2, 4, 2, 0>(amp, ua, ub);
        LD_T(tpC, rpC2, 4, 2, 2);
        fg1qF<2, 4, 2, 2>(amp, ua, ub);
    }
    // ---- C {q6:2 q7:4 q8:8 q9:1} ----
    FU0(8, 4, 8); FU0(9, 8, 1);

    // ---- T3 C->D (CROSS, del a2, SB=1): halfgate FU0(10,1,2) ----
    {
        F8 ua, ub; sld16(cf + 10*8, cf + 96 + 10*8, ua, ub);
        __syncthreads();             // T2 slots not wave-disjoint vs T3 stores
        const int tpC = tpC3f(l, w), tpD = tpD3f(l, w);
        ST_T(tpC, rpC3, 1, 0);
        __syncthreads();
        LD_T(tpD, rpD3, 2, 1, 0);
        __syncthreads();
        ST_T(tpC, rpC3, 1, 1);
        fg1qF<1, 2, 1, 0>(amp, ua, ub);
        __syncthreads();
        LD_T(tpD, rpD3, 2, 1, 1);
        fg1qF<1, 2, 1, 1>(amp, ua, ub);
    }
    // ---- D {q9:1 q10:2 q11:4 q0:8}: [CR0(11,0);U1(0)]; U1(9..11);
    //      L1 ring (11,0),(10,11),(9,10); expv 10,11 ----
    FU0(11, 2, 4);
    FU1_0();
    U1P(9, 1); U1P(10, 2); U1P(11, 4);
    CR1(11, 4, 8); CR1(10, 2, 4); CR1(9, 1, 2);
    EXPV(10, 2); EXPV(11, 4);

    // ---- T4 D->C' (internal, del a2, SB=1): halfgate U1P(7,4) ----
    // no barrier: T3-LD and T4-ST slots both carry a7a6=wave at f10,f9
    {
        F8 u7 = sld8(cf + 192 + 7*8);
        const int tpD = tpD3f(l, w), tpC = tpC4f(l, w);
        ST_T(tpD, rpD3, 1, 0);
        LD_T(tpC, rpC3, 4, 1, 0);
        ST_T(tpD, rpD3, 1, 1);
        g1qF<4, 1, 0>(amp, u7);
        LD_T(tpC, rpC3, 4, 1, 1);
        g1qF<4, 1, 1>(amp, u7);
    }
    // ---- C' {q6:2 q7:4 q8:8 q9:1}: U1(6,8); ring (8,9),(7,8),(6,7); expv 7,8,9 ----
    U1P(6, 2); U1P(8, 8);
    CR1(8, 8, 1); CR1(7, 4, 8); CR1(6, 2, 4);
    EXPV(9, 1); EXPV(8, 8); EXPV(7, 4);

    // ---- T5 C'->B' (CROSS, del a5, SB=2): halfgate U1P(3,1) ----
    // no leading barrier: T4-LD and T5-ST slots both carry a7a6=wave at f10,f9
    {
        F8 u3 = sld8(cf + 192 + 3*8);
        const int tpC = tpC5f(l, w), tpB = tpB5f(l, w);
        ST_T(tpC, rpC5, 2, 0);
        __syncthreads();
        LD_T(tpB, rpB5, 1, 2, 0);
        __syncthreads();
        ST_T(tpC, rpC5, 2, 2);
        g1qF<1, 2, 0>(amp, u3);
        __syncthreads();
        LD_T(tpB, rpB5, 1, 2, 2);
        g1qF<1, 2, 2>(amp, u3);
        __syncthreads();             // protect cross-wave reads from T6 stores
    }
    // ---- B' {q3:1 q4:4 q5:8 q6:2}: U1(4,5); ring (5,6),(4,5),(3,4); expv 4,5,6 ----
    U1P(4, 4); U1P(5, 8);
    CR1(5, 8, 2); CR1(4, 4, 8); CR1(3, 1, 4);
    EXPV(6, 2); EXPV(5, 8); EXPV(4, 4);

    // ---- T6 B'->A' (internal, del a8, SB=1): halfgate U1P(1,4) ----
    {
        F8 u1 = sld8(cf + 192 + 1*8);
        const int tpB = tpB1f(l, w), tpA = tpA1f(l, w);
        ST_T(tpB, rpB1, 1, 0);
        LD_T(tpA, rpA1, 4, 1, 0);
        ST_T(tpB, rpB1, 1, 1);
        g1qF<4, 1, 0>(amp, u1);
        LD_T(tpA, rpA1, 4, 1, 1);
        g1qF<4, 1, 1>(amp, u1);
    }
    // ---- A' {q0:8 q1:4 q2:2 q3:1}: U1(2); ring (2,3),(1,2),(0,1); expv 0..3 ----
    U1P(2, 2);
    CR1(2, 2, 1); CR1(1, 4, 2); CR1(0, 8, 4);
    EXPV(3, 1); EXPV(2, 2); EXPV(1, 4); EXPV(0, 8);

    // ---- combine 4 waves' partial features ----
    __syncthreads();                 // psi dead only after all waves' T6 loads
    float* fbuf = (float*)psi;       // [4][36]
    if (l < 12) {
        fbuf[w * 36 + l]      = fx;
        fbuf[w * 36 + 12 + l] = fy;
        fbuf[w * 36 + 24 + l] = fz;
    }
    __syncthreads();
    if (t < 10) {
        float a = bvec[t];
#pragma unroll
        for (int f = 0; f < 36; ++f)
            a += W[t * 36 + f] * (fbuf[f] + fbuf[36 + f] + fbuf[72 + f] + fbuf[108 + f]);
        out[(size_t)b * 10 + t] = a;
    }
}

extern "C" void kernel_launch(void* const* d_in, const int* in_sizes, int n_in,
                              void* d_out, int out_size, void* d_ws, size_t ws_size,
                              hipStream_t stream) {
    const float* sv     = (const float*)d_in[0];
    const float* angles = (const float*)d_in[1];
    const float* W      = (const float*)d_in[2];
    const float* bvec   = (const float*)d_in[3];
    float* out  = (float*)d_out;
    float* coef = (float*)d_ws;      // 320 floats of scratch
    int batch = in_sizes[0] / DIM;   // 2048
    prep_kernel<<<1, 64, 0, stream>>>(angles, coef);
    qsim_kernel<<<batch, 256, 0, stream>>>(sv, coef, W, bvec, out);
}